// Round 9
// baseline (470.418 us; speedup 1.0000x reference)
//
#include <hip/hip_runtime.h>

// ---------------------------------------------------------------------------
// QKGainAttention on MI355X (gfx950), round 16.
// R15 postmortem: BK=32 + vmcnt(0)/tile drain regressed QKV GEMM 130->165us
// (the m97 drain pathology). Second failed GEMM restructure -> REVERT to the
// R11/R14 schedule (130us, 33%) and declare it locally converged.
// R16 targets attn (~72us but ~3.6us of MFMA work = latency-bound at 2
// waves/SIMD). m=0 softmax => kt tiles are PURE SUMS (no running max), so
// split each tile across 8 waves: team0 = keys 0..31, team1 = keys 32..63.
// Per wave: 16 mfma32/tile, one sA (-24 VGPR); K/V tile amortized over 8
// waves; LDS 64KB -> still 2 blocks/CU but 16 waves/CU = 4/SIMD (2x TLP).
// Team-partial O/lrow combined once at end via LDS (team1 parks 4x16KB O
// partials in the then-dead Ks/Vt buffers, barrier-guarded); team0 writes y.
// f32 reorder only -> absmax within tolerance. Everything else R14-exact.
// ---------------------------------------------------------------------------

#define DEVINL __device__ __forceinline__

typedef unsigned short u16;
typedef __bf16 bf16x8 __attribute__((ext_vector_type(8)));
typedef float  f32x4  __attribute__((ext_vector_type(4)));
typedef float  f32x16 __attribute__((ext_vector_type(16)));
typedef short  short8 __attribute__((ext_vector_type(8)));
typedef u16    u16x4  __attribute__((ext_vector_type(4)));
typedef unsigned uint4x __attribute__((ext_vector_type(4)));

static constexpr int T_  = 2048;
static constexpr int C_  = 2048;
static constexpr int TC3 = 6144;   // 3*C

DEVINL u16 f2bf(float f) {
  union { float f; unsigned u; } v; v.f = f;
  unsigned r = v.u + 0x7FFFu + ((v.u >> 16) & 1u);   // RNE
  return (u16)(r >> 16);
}
DEVINL float bf2f(u16 s) {
  union { unsigned u; float f; } v; v.u = ((unsigned)s) << 16;
  return v.f;
}
DEVINL bf16x8 ld8(const u16* p) {
  return __builtin_bit_cast(bf16x8, *(const short8*)p);
}
DEVINL f32x4 mfma16(bf16x8 a, bf16x8 b, f32x4 c) {
  return __builtin_amdgcn_mfma_f32_16x16x32_bf16(a, b, c, 0, 0, 0);
}
DEVINL f32x16 mfma32(bf16x8 a, bf16x8 b, f32x16 c) {
  return __builtin_amdgcn_mfma_f32_32x32x16_bf16(a, b, c, 0, 0, 0);
}
DEVINL void async_cp16(const u16* gp, u16* lp) {
  __builtin_amdgcn_global_load_lds(
      (const __attribute__((address_space(1))) void*)gp,
      (__attribute__((address_space(3))) void*)lp, 16, 0, 0);
}
DEVINL unsigned cvtpk(float lo, float hi) {
  unsigned r;
  asm("v_cvt_pk_bf16_f32 %0, %1, %2" : "=v"(r) : "v"(lo), "v"(hi));
  return r;
}
DEVINL void plswap(unsigned& a, unsigned& b) {
  asm("v_permlane32_swap_b32 %0, %1" : "+v"(a), "+v"(b));
}
template<int N> DEVINL void vmwait() {
  if constexpr (N == 0)      asm volatile("s_waitcnt vmcnt(0)" ::: "memory");
  else if constexpr (N == 5) asm volatile("s_waitcnt vmcnt(5)" ::: "memory");
  else if constexpr (N == 7) asm volatile("s_waitcnt vmcnt(7)" ::: "memory");
  else if constexpr (N == 9) asm volatile("s_waitcnt vmcnt(9)" ::: "memory");
}

// ---------------- fused dtype casts (3 inputs, one launch) ----------------
__global__ __launch_bounds__(256) void k_cast_all(
    const float* __restrict__ x, const int* __restrict__ aw,
    const int* __restrict__ pw, u16* __restrict__ xb,
    u16* __restrict__ wab, u16* __restrict__ wpb) {
  const int b = blockIdx.x;
  if (b < 8192) {
    long i = (long)(b * 256 + threadIdx.x) * 4;
    float4 v = *(const float4*)(x + i);
    u16x4 o; o.x = f2bf(v.x); o.y = f2bf(v.y); o.z = f2bf(v.z); o.w = f2bf(v.w);
    *(u16x4*)(xb + i) = o;
  } else {
    const int* in; u16* out; int lb;
    if (b < 20480) { in = aw; out = wab; lb = b - 8192; }
    else           { in = pw; out = wpb; lb = b - 20480; }
    long i = (long)(lb * 256 + threadIdx.x) * 4;
    int4 v = *(const int4*)(in + i);
    u16x4 o; o.x = f2bf((float)v.x); o.y = f2bf((float)v.y);
    o.z = f2bf((float)v.z); o.w = f2bf((float)v.w);
    *(u16x4*)(out + i) = o;
  }
}

// ---------------- GEMM 256x192 8-phase counted-vmcnt (QKV) -- R11 ----------
// LDS: [buf][row][k 0..63] bf16, XOR-swizzled: (row,k) at row*64 +
// (k ^ ((row&7)*8)).  Staging unit = 64-row quarter (8KB = 1 gload_lds
// x16B / thread @512thr); linear LDS dest + inverse-swizzled global source.
template<int SZ>
DEVINL void stage_q(const u16* __restrict__ G, long brow, long K, int tt, int qi,
                    u16 (&L)[2][SZ], int w, int lane) {
  const int sr = w * 8 + (lane >> 3);      // row within quarter
  const int sc = lane & 7;                 // 16B chunk
  const long grow = brow + qi * 64 + sr;
  async_cp16(G + grow * K + (long)(tt << 6) + ((sc ^ (sr & 7)) << 3),
             &L[tt & 1][(qi * 64 + w * 8) * 64]);
}

template<int WP1, int WP3, bool ISS0, bool ISS123, bool LAST>
DEVINL void kstep256(int t, const u16* __restrict__ A, const u16* __restrict__ Bt,
                     long K, long bm, long bn,
                     u16 (&As)[2][256 * 64], u16 (&Bs)[2][192 * 64],
                     f32x4 (&acc)[8][3], int w, int lane) {
  const int l15 = lane & 15, quad = lane >> 4;
  const int wm = (w & 1) * 128;
  const int wn = (w >> 1) * 48;
  const int buf = t & 1;

  auto rdA = [&](int mi, int kc) -> bf16x8 {
    const int row = wm + mi * 16 + l15;
    const int k0 = kc * 32 + quad * 8;
    return ld8(&As[buf][row * 64 + (k0 ^ ((row & 7) * 8))]);
  };
  auto rdB = [&](int ni, int kc) -> bf16x8 {
    const int row = wn + ni * 16 + l15;
    const int k0 = kc * 32 + quad * 8;
    return ld8(&Bs[buf][row * 64 + (k0 ^ ((row & 7) * 8))]);
  };

  // ---- phase 0: read A-lo(8) + B-lo(4); issue (t+1).Aq1,Aq3; MFMA Q00 ----
  bf16x8 af[4][2], bfl[2][2];
#pragma unroll
  for (int mi = 0; mi < 4; ++mi) { af[mi][0] = rdA(mi, 0); af[mi][1] = rdA(mi, 1); }
#pragma unroll
  for (int ni = 0; ni < 2; ++ni) { bfl[ni][0] = rdB(ni, 0); bfl[ni][1] = rdB(ni, 1); }
  if constexpr (ISS0) {
    stage_q(A, bm, K, t + 1, 1, As, w, lane);
    stage_q(A, bm, K, t + 1, 3, As, w, lane);
  }
  __builtin_amdgcn_s_barrier();
  __builtin_amdgcn_s_setprio(1);
#pragma unroll
  for (int mi = 0; mi < 4; ++mi)
#pragma unroll
    for (int ni = 0; ni < 2; ++ni) {
      acc[mi][ni] = mfma16(af[mi][0], bfl[ni][0], acc[mi][ni]);
      acc[mi][ni] = mfma16(af[mi][1], bfl[ni][1], acc[mi][ni]);
    }
  __builtin_amdgcn_s_setprio(0);
  __builtin_amdgcn_s_barrier();

  // ---- phase 1: read B-hi(2); issue (t+2).Aq0,Aq2; MFMA Q01; wait WP1 ----
  bf16x8 bfh[2];
  bfh[0] = rdB(2, 0); bfh[1] = rdB(2, 1);
  if constexpr (ISS123) {
    stage_q(A, bm, K, t + 2, 0, As, w, lane);
    stage_q(A, bm, K, t + 2, 2, As, w, lane);
  }
  __builtin_amdgcn_s_barrier();
  __builtin_amdgcn_s_setprio(1);
#pragma unroll
  for (int mi = 0; mi < 4; ++mi) {
    acc[mi][2] = mfma16(af[mi][0], bfh[0], acc[mi][2]);
    acc[mi][2] = mfma16(af[mi][1], bfh[1], acc[mi][2]);
  }
  __builtin_amdgcn_s_setprio(0);
  vmwait<WP1>();
  __builtin_amdgcn_s_barrier();

  // ---- phase 2: read A-hi(8); issue (t+2).Bq0,Bq1; MFMA Q11 ----
  bf16x8 af2[4][2];
#pragma unroll
  for (int mi = 0; mi < 4; ++mi) { af2[mi][0] = rdA(4 + mi, 0); af2[mi][1] = rdA(4 + mi, 1); }
  if constexpr (ISS123) {
    stage_q(Bt, bn, K, t + 2, 0, Bs, w, lane);
    stage_q(Bt, bn, K, t + 2, 1, Bs, w, lane);
  }
  __builtin_amdgcn_s_barrier();
  __builtin_amdgcn_s_setprio(1);
#pragma unroll
  for (int mi = 0; mi < 4; ++mi) {
    acc[4 + mi][2] = mfma16(af2[mi][0], bfh[0], acc[4 + mi][2]);
    acc[4 + mi][2] = mfma16(af2[mi][1], bfh[1], acc[4 + mi][2]);
  }
  __builtin_amdgcn_s_setprio(0);
  __builtin_amdgcn_s_barrier();

  // ---- phase 3: issue (t+2).Bq2; MFMA Q10; wait WP3 ----
  if constexpr (ISS123) {
    stage_q(Bt, bn, K, t + 2, 2, Bs, w, lane);
  }
  __builtin_amdgcn_s_setprio(1);
#pragma unroll
  for (int mi = 0; mi < 4; ++mi)
#pragma unroll
    for (int ni = 0; ni < 2; ++ni) {
      acc[4 + mi][ni] = mfma16(af2[mi][0], bfl[ni][0], acc[4 + mi][ni]);
      acc[4 + mi][ni] = mfma16(af2[mi][1], bfl[ni][1], acc[4 + mi][ni]);
    }
  __builtin_amdgcn_s_setprio(0);
  if constexpr (!LAST) {
    vmwait<WP3>();
    __builtin_amdgcn_s_barrier();
  }
}

__global__ __launch_bounds__(512, 2) void k_gemm256(
    const u16* __restrict__ A, const u16* __restrict__ Bt,
    const float* __restrict__ scale, u16* __restrict__ C,
    int N, long K) {
  __shared__ u16 As[2][256 * 64];
  __shared__ u16 Bs[2][192 * 64];
  const int tid = threadIdx.x, w = tid >> 6, lane = tid & 63;
  const long bm = (long)blockIdx.y * 256;
  const long bn = (long)blockIdx.x * 192;
  const int nt = (int)(K >> 6);            // K-tiles of 64 (=32 here)

  // prologue (R11 exact, 12 issues): tile0 all 7 + tile1 {Aq0,Aq2,B0,B1,B2};
  // vmcnt(5) -> tile0's 7 landed, tile1's 5 in flight.
  stage_q(A, bm, K, 0, 0, As, w, lane); stage_q(A, bm, K, 0, 2, As, w, lane);
  stage_q(Bt, bn, K, 0, 0, Bs, w, lane); stage_q(Bt, bn, K, 0, 1, Bs, w, lane);
  stage_q(Bt, bn, K, 0, 2, Bs, w, lane);
  stage_q(A, bm, K, 0, 1, As, w, lane); stage_q(A, bm, K, 0, 3, As, w, lane);
  stage_q(A, bm, K, 1, 0, As, w, lane); stage_q(A, bm, K, 1, 2, As, w, lane);
  stage_q(Bt, bn, K, 1, 0, Bs, w, lane); stage_q(Bt, bn, K, 1, 1, Bs, w, lane);
  stage_q(Bt, bn, K, 1, 2, Bs, w, lane);
  vmwait<5>();
  __builtin_amdgcn_s_barrier();

  f32x4 acc[8][3] = {};
  int t = 0;
  for (; t < nt - 2; ++t)
    kstep256<9, 5, true, true, false>(t, A, Bt, K, bm, bn, As, Bs, acc, w, lane);
  kstep256<7, 0, true, false, false>(nt - 2, A, Bt, K, bm, bn, As, Bs, acc, w, lane);
  kstep256<0, 0, false, false, true>(nt - 1, A, Bt, K, bm, bn, As, Bs, acc, w, lane);

  const int l15 = lane & 15, quad = lane >> 4;
  const int wm = (w & 1) * 128, wn = (w >> 1) * 48;
#pragma unroll
  for (int ni = 0; ni < 3; ++ni) {
    const long col = bn + wn + ni * 16 + l15;
    const float sc = scale[col];
#pragma unroll
    for (int mi = 0; mi < 8; ++mi) {
      const long row0 = bm + wm + mi * 16 + quad * 4;
#pragma unroll
      for (int r = 0; r < 4; ++r)
        C[(row0 + r) * (long)N + col] = f2bf(acc[mi][ni][r] * sc);
    }
  }
}

// ---------------- GEMM 128x256 1-round (proj), f32 out ----------------------
__global__ __launch_bounds__(512, 2) void k_gemm_proj(
    const u16* __restrict__ A, const u16* __restrict__ Bt,
    const float* __restrict__ scale, float* __restrict__ C,
    int N, long K) {
  __shared__ u16 As[2][128 * 64];
  __shared__ u16 Bs[2][256 * 64];
  const int tid = threadIdx.x, w = tid >> 6, lane = tid & 63;
  const int l15 = lane & 15, quad = lane >> 4;
  const int wm = (w & 1) * 64, wn = (w >> 1) * 64;
  const long bm = (long)blockIdx.y * 128;
  const long bn = (long)blockIdx.x * 256;
  const int nt = (int)(K >> 6);

  auto rdA = [&](int mi, int kc, int buf) -> bf16x8 {
    const int row = wm + mi * 16 + l15;
    const int k0 = kc * 32 + quad * 8;
    return ld8(&As[buf][row * 64 + (k0 ^ ((row & 7) * 8))]);
  };
  auto rdB = [&](int ni, int kc, int buf) -> bf16x8 {
    const int row = wn + ni * 16 + l15;
    const int k0 = kc * 32 + quad * 8;
    return ld8(&Bs[buf][row * 64 + (k0 ^ ((row & 7) * 8))]);
  };

  // prologue: tile0's 6 quarters, full drain
  stage_q(A, bm, K, 0, 0, As, w, lane); stage_q(A, bm, K, 0, 1, As, w, lane);
  stage_q(Bt, bn, K, 0, 0, Bs, w, lane); stage_q(Bt, bn, K, 0, 1, Bs, w, lane);
  stage_q(Bt, bn, K, 0, 2, Bs, w, lane); stage_q(Bt, bn, K, 0, 3, Bs, w, lane);
  vmwait<0>();
  __builtin_amdgcn_s_barrier();

  f32x4 acc[4][4] = {};
  for (int t = 0; t < nt; ++t) {
    const int buf = t & 1;
    const bool iss = (t < nt - 1);
    bf16x8 a01[2][2], a23[2][2], b01[2][2], b23[2][2];

    // ---- P0: stage (t+1).Bq0,Bq1,Aq0; read a01(4)+b01(4); MFMA Q00 ----
    if (iss) {
      stage_q(Bt, bn, K, t + 1, 0, Bs, w, lane);
      stage_q(Bt, bn, K, t + 1, 1, Bs, w, lane);
      stage_q(A,  bm, K, t + 1, 0, As, w, lane);
    }
#pragma unroll
    for (int mi = 0; mi < 2; ++mi) { a01[mi][0] = rdA(mi, 0, buf); a01[mi][1] = rdA(mi, 1, buf); }
#pragma unroll
    for (int ni = 0; ni < 2; ++ni) { b01[ni][0] = rdB(ni, 0, buf); b01[ni][1] = rdB(ni, 1, buf); }
    __builtin_amdgcn_s_barrier();
    __builtin_amdgcn_s_setprio(1);
#pragma unroll
    for (int mi = 0; mi < 2; ++mi)
#pragma unroll
      for (int ni = 0; ni < 2; ++ni) {
        acc[mi][ni] = mfma16(a01[mi][0], b01[ni][0], acc[mi][ni]);
        acc[mi][ni] = mfma16(a01[mi][1], b01[ni][1], acc[mi][ni]);
      }
    __builtin_amdgcn_s_setprio(0);
    __builtin_amdgcn_s_barrier();

    // ---- P1: stage (t+1).Bq2,Bq3,Aq1; read b23(4); MFMA Q01 ----
    if (iss) {
      stage_q(Bt, bn, K, t + 1, 2, Bs, w, lane);
      stage_q(Bt, bn, K, t + 1, 3, Bs, w, lane);
      stage_q(A,  bm, K, t + 1, 1, As, w, lane);
    }
#pragma unroll
    for (int ni = 0; ni < 2; ++ni) { b23[ni][0] = rdB(2 + ni, 0, buf); b23[ni][1] = rdB(2 + ni, 1, buf); }
    __builtin_amdgcn_s_barrier();
    __builtin_amdgcn_s_setprio(1);
#pragma unroll
    for (int mi = 0; mi < 2; ++mi)
#pragma unroll
      for (int ni = 0; ni < 2; ++ni) {
        acc[mi][2 + ni] = mfma16(a01[mi][0], b23[ni][0], acc[mi][2 + ni]);
        acc[mi][2 + ni] = mfma16(a01[mi][1], b23[ni][1], acc[mi][2 + ni]);
      }
    __builtin_amdgcn_s_setprio(0);
    __builtin_amdgcn_s_barrier();

    // ---- P2: read a23(4); MFMA Q11 ----
#pragma unroll
    for (int mi = 0; mi < 2; ++mi) { a23[mi][0] = rdA(2 + mi, 0, buf); a23[mi][1] = rdA(2 + mi, 1, buf); }
    __builtin_amdgcn_s_barrier();
    __builtin_amdgcn_s_setprio(1);
#pragma unroll
    for (int mi = 0; mi < 2; ++mi)
#pragma unroll
      for (int ni = 0; ni < 2; ++ni) {
        acc[2 + mi][2 + ni] = mfma16(a23[mi][0], b23[ni][0], acc[2 + mi][2 + ni]);
        acc[2 + mi][2 + ni] = mfma16(a23[mi][1], b23[ni][1], acc[2 + mi][2 + ni]);
      }
    __builtin_amdgcn_s_setprio(0);
    __builtin_amdgcn_s_barrier();

    // ---- P3: MFMA Q10; end-of-tile drain (skipped on last) ----
    __builtin_amdgcn_s_setprio(1);
#pragma unroll
    for (int mi = 0; mi < 2; ++mi)
#pragma unroll
      for (int ni = 0; ni < 2; ++ni) {
        acc[2 + mi][ni] = mfma16(a23[mi][0], b01[ni][0], acc[2 + mi][ni]);
        acc[2 + mi][ni] = mfma16(a23[mi][1], b01[ni][1], acc[2 + mi][ni]);
      }
    __builtin_amdgcn_s_setprio(0);
    if (iss) {
      vmwait<0>();
      __builtin_amdgcn_s_barrier();
    }
  }

  // ---- epilogue: f32 out with per-col scale ----
#pragma unroll
  for (int ni = 0; ni < 4; ++ni) {
    const long col = bn + wn + ni * 16 + l15;
    const float sc = scale[col];
#pragma unroll
    for (int mi = 0; mi < 4; ++mi) {
      const long row0 = bm + wm + mi * 16 + quad * 4;
#pragma unroll
      for (int r = 0; r < 4; ++r)
        C[(row0 + r) * (long)N + col] = acc[mi][ni][r] * sc;
    }
  }
}

// ---------------- fused l2norm(q,k) + V transpose (disjoint regions) --------
__global__ __launch_bounds__(256) void k_norm_vt(u16* __restrict__ qkv,
                                                 const float* __restrict__ qk_gain,
                                                 u16* __restrict__ vt) {
  const int b = blockIdx.x;
  if (b < 4096) {
    const int token = b;
    const int wave = threadIdx.x >> 6, lane = threadIdx.x & 63;
    const float g = qk_gain[0];
    const float qmul = g * g * 1.44269504f * 0.08838834764f;
    u16* rowp = qkv + (long)token * TC3;
#pragma unroll
    for (int s = 0; s < 8; ++s) {
      const int seg = wave * 8 + s;
      const int isK = seg >> 4;
      const int h = seg & 15;
      u16* ptr = rowp + isK * C_ + h * 128 + lane * 2;
      unsigned pv = *(const unsigned*)ptr;
      float a = bf2f((u16)(pv & 0xffffu));
      float bb = bf2f((u16)(pv >> 16));
      float ss = a * a + bb * bb;
#pragma unroll
      for (int m = 1; m <= 32; m <<= 1) ss += __shfl_xor(ss, m);
      float denom = fmaxf(sqrtf(ss), 1e-12f);
      float f = (isK ? 1.0f : qmul) / denom;
      u16 o0 = f2bf(a * f), o1 = f2bf(bb * f);
      *(unsigned*)ptr = (unsigned)o0 | ((unsigned)o1 << 16);
    }
  } else {
    const int v = b - 4096;
    const int t0 = (v & 31) * 64;
    const int h = (v >> 5) & 15;
    const int bz = v >> 9;
    const int t = threadIdx.x & 63;
    const int d0 = threadIdx.x >> 6;       // 0..3
    const long tokbase = (long)bz * T_;
    const u16* src = qkv + (tokbase + t0 + t) * (long)TC3 + 2 * C_ + h * 128;
    u16* dst = vt + ((long)(bz * 16 + h) * 128) * (long)T_ + t0 + t;
#pragma unroll
    for (int dd = 0; dd < 32; ++dd) {
      const int d = dd * 4 + d0;
      dst[(long)d * T_] = src[d];
    }
  }
}

// ---------------- flash attention (causal), m=0 softmax, 8-wave team split --
// 512 thr = 8 waves. team = w>>2 (0: keys 0..31 of each tile, 1: keys
// 32..63); strip ws = w&3 (32 queries each). Per wave 16 mfma32/tile; K/V
// tile amortized over 8 waves; 16 waves/CU = 4/SIMD. Partial O/lrow summed
// at the end via LDS (team1 parks O in the dead Ks/Vt buffers, 4x16KB).
__global__ __launch_bounds__(512, 4) void k_attn(const u16* __restrict__ qkv,
                                                 const u16* __restrict__ vtg,
                                                 u16* __restrict__ y) {
  const int qt = blockIdx.z ? (15 - blockIdx.x) : blockIdx.x;
  const int h  = blockIdx.y;
  const int bz = blockIdx.z;
  const int tid = threadIdx.x, w = tid >> 6, lane = tid & 63;
  const int m31 = lane & 31, hi = lane >> 5;
  const int team = w >> 2, ws = w & 3;

  __shared__ u16 Ks[2][64 * 128];
  __shared__ u16 Vt[2][128 * 64];
  __shared__ float lr[4][64];

  const long tokbase = (long)bz * T_;
  const int qbase = qt * 128 + ws * 32;    // 32 queries per wave strip
  const u16* vbase = vtg + ((long)(bz * 16 + h) * 128) * (long)T_;
  const u16* kbase = qkv + tokbase * TC3 + C_ + h * 128;

  // Q B-frags (32x32x16: col=lane&31=query, k=d=kc*16+hi*8+i)
  bf16x8 qf[8];
  {
    const u16* qp = qkv + (tokbase + qbase + m31) * (long)TC3 + h * 128 + hi * 8;
#pragma unroll
    for (int kc = 0; kc < 8; ++kc)
      qf[kc] = ld8(qp + kc * 16);
  }

  f32x16 o[4];                             // O^T partial (team's 32-key half)
#pragma unroll
  for (int i = 0; i < 4; ++i)
#pragma unroll
    for (int r = 0; r < 16; ++r) o[i][r] = 0.f;
  f32x4 lacc = {0.f, 0.f, 0.f, 0.f};

  auto stage = [&](int ktb, int b2) {
#pragma unroll
    for (int j = 0; j < 2; ++j) {          // 512 thr: 2 K + 2 V issues each
      const int t = w * 2 + j;
      const int p = t * 64 + lane;
      const int r  = p >> 4, ck = p & 15;          // K: row r, chunk ck
      async_cp16(kbase + (long)(ktb + r) * TC3 + ((ck ^ (r & 15)) * 8),
                 &Ks[b2][t * 512]);
      const int d  = p >> 3, cv = p & 7;           // V: row d, chunk cv
      async_cp16(vbase + (long)d * T_ + ktb + ((cv ^ (d & 7)) * 8),
                 &Vt[b2][t * 512]);
    }
  };

  stage(0, 0);
  __syncthreads();                         // drain tile-0 staging
  int b = 0;
  const int ktmax = 2 * qt + 1;

  for (int kt = 0; kt <= ktmax; ++kt) {
    const int ktb = kt * 64;
    if (kt < ktmax) stage(ktb + 64, b ^ 1);

    const int kteam = ktb + team * 32;     // first key of this wave's half
    if (kteam <= qbase + 31) {             // skip fully-masked halves
      // --- S^T = K.Q^T over the team's 32 keys ---
      f32x16 sA;
#pragma unroll
      for (int r = 0; r < 16; ++r) sA[r] = 0.f;
      __builtin_amdgcn_s_setprio(1);
#pragma unroll
      for (int kc = 0; kc < 8; ++kc) {
        bf16x8 kf = ld8(&Ks[b][(team * 32 + m31) * 128 +
                               (((2 * kc + hi) ^ (lane & 15)) * 8)]);
        sA = mfma32(kf, qf[kc], sA);
      }
      __builtin_amdgcn_s_setprio(0);

      // --- causal mask ---
      if (kteam + 31 > qbase) {
        const int qq = qbase + m31;
#pragma unroll
        for (int r = 0; r < 16; ++r) {
          const int key = kteam + (r & 3) + 8 * (r >> 2) + 4 * hi;
          if (key > qq) sA[r] = -1e30f;
        }
      }
      // --- m=0 softmax: P = exp2(s) ---
#pragma unroll
      for (int r = 0; r < 16; ++r) {
        float p = __builtin_amdgcn_exp2f(sA[r]);
        sA[r] = p;
        lacc[r & 3] += p;
      }

      // --- P^T B-frags via cvt_pk + permlane32_swap ---
      bf16x8 pb[2];
#pragma unroll
      for (int j = 0; j < 2; ++j) {
        unsigned w0a = cvtpk(sA[8 * j + 0], sA[8 * j + 1]);
        unsigned w1a = cvtpk(sA[8 * j + 2], sA[8 * j + 3]);
        unsigned w0b = cvtpk(sA[8 * j + 4], sA[8 * j + 5]);
        unsigned w1b = cvtpk(sA[8 * j + 6], sA[8 * j + 7]);
        plswap(w0a, w0b);
        plswap(w1a, w1b);
        uint4x t; t.x = w0a; t.y = w1a; t.z = w0b; t.w = w1b;
        pb[j] = __builtin_bit_cast(bf16x8, t);
      }

      // --- O^T += V^T.P^T over the team's 2 key-slots ---
      __builtin_amdgcn_s_setprio(1);
#pragma unroll
      for (int db = 0; db < 4; ++db)
#pragma unroll
        for (int kl = 0; kl < 2; ++kl) {
          const int ks = team * 2 + kl;
          bf16x8 vf = ld8(&Vt[b][(db * 32 + m31) * 64 +
                                 (((2 * ks + hi) ^ (m31 & 7)) * 8)]);
          o[db] = mfma32(vf, pb[kl], o[db]);
        }
      __builtin_amdgcn_s_setprio(0);
    }

    if (kt < ktmax) __syncthreads();       // drains prefetch + guards buffers
    b ^= 1;
  }

  // --- team combine: lrow partial (quad-reduced) then O/lrow exchange ---
  float lrow = lacc[0] + lacc[1] + lacc[2] + lacc[3];
  lrow += __shfl_xor(lrow, 32);

  __syncthreads();                         // all tile compute done; LDS free
  {
    float* ex = (ws == 0) ? (float*)&Ks[0][0]
              : (ws == 1) ? (float*)&Ks[1][0]
              : (ws == 2) ? (float*)&Vt[0][0]
              :             (float*)&Vt[1][0];
    if (team == 1) {
#pragma unroll
      for (int db = 0; db < 4; ++db)
#pragma unroll
        for (int r = 0; r < 16; ++r)
          ex[(db * 16 + r) * 64 + lane] = o[db][r];
      lr[ws][lane] = lrow;
    }
    __syncthreads();
    if (team == 0) {
#pragma unroll
      for (int db = 0; db < 4; ++db)
#pragma unroll
        for (int r = 0; r < 16; ++r)
          o[db][r] += ex[(db * 16 + r) * 64 + lane];
      lrow += lr[ws][lane];

      const float inv_l = 1.0f / lrow;
      u16* yp = y + (tokbase + qbase + m31) * (long)C_ + h * 128 + 4 * hi;
#pragma unroll
      for (int db = 0; db < 4; ++db)
#pragma unroll
        for (int g = 0; g < 4; ++g) {
          u16x4 pk;
#pragma unroll
          for (int r = 0; r < 4; ++r) pk[r] = f2bf(o[db][g * 4 + r] * inv_l);
          *(u16x4*)(yp + db * 32 + g * 8) = pk;
        }
    }
  }
}

// ---------------------------------------------------------------------------
extern "C" void kernel_launch(void* const* d_in, const int* in_sizes, int n_in,
                              void* d_out, int out_size, void* d_ws, size_t ws_size,
                              hipStream_t stream) {
  const float* x    = (const float*)d_in[0];
  const int*   aw   = (const int*)d_in[1];
  const float* asc  = (const float*)d_in[2];
  const int*   pw   = (const int*)d_in[3];
  const float* psc  = (const float*)d_in[4];
  const float* gain = (const float*)d_in[5];

  char* ws = (char*)d_ws;
  u16* xb  = (u16*)(ws);                         // 16.78 MB (reused as Vt_g)
  u16* wab = (u16*)(ws + 16777216UL);
  u16* wpb = (u16*)(ws + 41943040UL);
  u16* qkv = (u16*)(ws + 50331648UL);
  u16* yb  = (u16*)(ws + 100663296UL);
  u16* vtg = xb;                                 // x_bf16 dead after QKV GEMM

  k_cast_all<<<24576, 256, 0, stream>>>(x, aw, pw, xb, wab, wpb);
  k_gemm256<<<dim3(32, 16), 512, 0, stream>>>(xb, wab, asc, qkv, TC3, (long)C_);
  k_norm_vt<<<5120, 256, 0, stream>>>(qkv, gain, vtg);
  k_attn<<<dim3(16, 16, 2), 512, 0, stream>>>(qkv, vtg, yb);
  k_gemm_proj<<<dim3(8, 32), 512, 0, stream>>>(yb, wpb, psc, (float*)d_out, C_, (long)C_);
}

// Round 10
// 396.851 us; speedup vs baseline: 1.1854x; 1.1854x over previous
//
#include <hip/hip_runtime.h>

// ---------------------------------------------------------------------------
// QKGainAttention on MI355X (gfx950), round 17.
// R16 postmortem: attn 8-wave team-split regressed (416->470): (512,4)
// bounds force 128-VGPR vs ~140 needed (spill), and LDS 65KB caps 2
// blocks/CU anyway so TLP never doubled. REVERT attn to R14-exact.
// R17: k_gemm_proj gets R11's 2-tile-lookahead counted-vmcnt (removes the
// per-tile vmcnt(0) drain = m97 pathology, proven -25% on this shape in
// R15). Ledger: cur-buf B reads drain by P1's closing barrier, A reads by
// P2's -> stage (t+2).Bq0..3 in P2, (t+2).Aq0,Aq1 in P3; end-of-tile
// vmcnt(6) lands exactly t+1's 6 quarters (12 in flight max). Prologue:
// tile0+tile1 (12 issues), vmcnt(6). Tail: nt-2 waits 0, nt-1 free.
// MFMA order unchanged = bit-identical. gemm256/attn/casts R14-verbatim.
// ---------------------------------------------------------------------------

#define DEVINL __device__ __forceinline__

typedef unsigned short u16;
typedef __bf16 bf16x8 __attribute__((ext_vector_type(8)));
typedef float  f32x4  __attribute__((ext_vector_type(4)));
typedef float  f32x16 __attribute__((ext_vector_type(16)));
typedef short  short8 __attribute__((ext_vector_type(8)));
typedef u16    u16x4  __attribute__((ext_vector_type(4)));
typedef unsigned uint4x __attribute__((ext_vector_type(4)));

static constexpr int T_  = 2048;
static constexpr int C_  = 2048;
static constexpr int TC3 = 6144;   // 3*C

DEVINL u16 f2bf(float f) {
  union { float f; unsigned u; } v; v.f = f;
  unsigned r = v.u + 0x7FFFu + ((v.u >> 16) & 1u);   // RNE
  return (u16)(r >> 16);
}
DEVINL float bf2f(u16 s) {
  union { unsigned u; float f; } v; v.u = ((unsigned)s) << 16;
  return v.f;
}
DEVINL bf16x8 ld8(const u16* p) {
  return __builtin_bit_cast(bf16x8, *(const short8*)p);
}
DEVINL f32x4 mfma16(bf16x8 a, bf16x8 b, f32x4 c) {
  return __builtin_amdgcn_mfma_f32_16x16x32_bf16(a, b, c, 0, 0, 0);
}
DEVINL f32x16 mfma32(bf16x8 a, bf16x8 b, f32x16 c) {
  return __builtin_amdgcn_mfma_f32_32x32x16_bf16(a, b, c, 0, 0, 0);
}
DEVINL void async_cp16(const u16* gp, u16* lp) {
  __builtin_amdgcn_global_load_lds(
      (const __attribute__((address_space(1))) void*)gp,
      (__attribute__((address_space(3))) void*)lp, 16, 0, 0);
}
DEVINL unsigned cvtpk(float lo, float hi) {
  unsigned r;
  asm("v_cvt_pk_bf16_f32 %0, %1, %2" : "=v"(r) : "v"(lo), "v"(hi));
  return r;
}
DEVINL void plswap(unsigned& a, unsigned& b) {
  asm("v_permlane32_swap_b32 %0, %1" : "+v"(a), "+v"(b));
}
template<int N> DEVINL void vmwait() {
  if constexpr (N == 0)      asm volatile("s_waitcnt vmcnt(0)" ::: "memory");
  else if constexpr (N == 5) asm volatile("s_waitcnt vmcnt(5)" ::: "memory");
  else if constexpr (N == 6) asm volatile("s_waitcnt vmcnt(6)" ::: "memory");
  else if constexpr (N == 7) asm volatile("s_waitcnt vmcnt(7)" ::: "memory");
  else if constexpr (N == 9) asm volatile("s_waitcnt vmcnt(9)" ::: "memory");
}

// ---------------- fused dtype casts (3 inputs, one launch) ----------------
__global__ __launch_bounds__(256) void k_cast_all(
    const float* __restrict__ x, const int* __restrict__ aw,
    const int* __restrict__ pw, u16* __restrict__ xb,
    u16* __restrict__ wab, u16* __restrict__ wpb) {
  const int b = blockIdx.x;
  if (b < 8192) {
    long i = (long)(b * 256 + threadIdx.x) * 4;
    float4 v = *(const float4*)(x + i);
    u16x4 o; o.x = f2bf(v.x); o.y = f2bf(v.y); o.z = f2bf(v.z); o.w = f2bf(v.w);
    *(u16x4*)(xb + i) = o;
  } else {
    const int* in; u16* out; int lb;
    if (b < 20480) { in = aw; out = wab; lb = b - 8192; }
    else           { in = pw; out = wpb; lb = b - 20480; }
    long i = (long)(lb * 256 + threadIdx.x) * 4;
    int4 v = *(const int4*)(in + i);
    u16x4 o; o.x = f2bf((float)v.x); o.y = f2bf((float)v.y);
    o.z = f2bf((float)v.z); o.w = f2bf((float)v.w);
    *(u16x4*)(out + i) = o;
  }
}

// ---------------- GEMM 256x192 8-phase counted-vmcnt (QKV) -- R11 ----------
// LDS: [buf][row][k 0..63] bf16, XOR-swizzled: (row,k) at row*64 +
// (k ^ ((row&7)*8)).  Staging unit = 64-row quarter (8KB = 1 gload_lds
// x16B / thread @512thr); linear LDS dest + inverse-swizzled global source.
template<int SZ>
DEVINL void stage_q(const u16* __restrict__ G, long brow, long K, int tt, int qi,
                    u16 (&L)[2][SZ], int w, int lane) {
  const int sr = w * 8 + (lane >> 3);      // row within quarter
  const int sc = lane & 7;                 // 16B chunk
  const long grow = brow + qi * 64 + sr;
  async_cp16(G + grow * K + (long)(tt << 6) + ((sc ^ (sr & 7)) << 3),
             &L[tt & 1][(qi * 64 + w * 8) * 64]);
}

template<int WP1, int WP3, bool ISS0, bool ISS123, bool LAST>
DEVINL void kstep256(int t, const u16* __restrict__ A, const u16* __restrict__ Bt,
                     long K, long bm, long bn,
                     u16 (&As)[2][256 * 64], u16 (&Bs)[2][192 * 64],
                     f32x4 (&acc)[8][3], int w, int lane) {
  const int l15 = lane & 15, quad = lane >> 4;
  const int wm = (w & 1) * 128;
  const int wn = (w >> 1) * 48;
  const int buf = t & 1;

  auto rdA = [&](int mi, int kc) -> bf16x8 {
    const int row = wm + mi * 16 + l15;
    const int k0 = kc * 32 + quad * 8;
    return ld8(&As[buf][row * 64 + (k0 ^ ((row & 7) * 8))]);
  };
  auto rdB = [&](int ni, int kc) -> bf16x8 {
    const int row = wn + ni * 16 + l15;
    const int k0 = kc * 32 + quad * 8;
    return ld8(&Bs[buf][row * 64 + (k0 ^ ((row & 7) * 8))]);
  };

  // ---- phase 0: read A-lo(8) + B-lo(4); issue (t+1).Aq1,Aq3; MFMA Q00 ----
  bf16x8 af[4][2], bfl[2][2];
#pragma unroll
  for (int mi = 0; mi < 4; ++mi) { af[mi][0] = rdA(mi, 0); af[mi][1] = rdA(mi, 1); }
#pragma unroll
  for (int ni = 0; ni < 2; ++ni) { bfl[ni][0] = rdB(ni, 0); bfl[ni][1] = rdB(ni, 1); }
  if constexpr (ISS0) {
    stage_q(A, bm, K, t + 1, 1, As, w, lane);
    stage_q(A, bm, K, t + 1, 3, As, w, lane);
  }
  __builtin_amdgcn_s_barrier();
  __builtin_amdgcn_s_setprio(1);
#pragma unroll
  for (int mi = 0; mi < 4; ++mi)
#pragma unroll
    for (int ni = 0; ni < 2; ++ni) {
      acc[mi][ni] = mfma16(af[mi][0], bfl[ni][0], acc[mi][ni]);
      acc[mi][ni] = mfma16(af[mi][1], bfl[ni][1], acc[mi][ni]);
    }
  __builtin_amdgcn_s_setprio(0);
  __builtin_amdgcn_s_barrier();

  // ---- phase 1: read B-hi(2); issue (t+2).Aq0,Aq2; MFMA Q01; wait WP1 ----
  bf16x8 bfh[2];
  bfh[0] = rdB(2, 0); bfh[1] = rdB(2, 1);
  if constexpr (ISS123) {
    stage_q(A, bm, K, t + 2, 0, As, w, lane);
    stage_q(A, bm, K, t + 2, 2, As, w, lane);
  }
  __builtin_amdgcn_s_barrier();
  __builtin_amdgcn_s_setprio(1);
#pragma unroll
  for (int mi = 0; mi < 4; ++mi) {
    acc[mi][2] = mfma16(af[mi][0], bfh[0], acc[mi][2]);
    acc[mi][2] = mfma16(af[mi][1], bfh[1], acc[mi][2]);
  }
  __builtin_amdgcn_s_setprio(0);
  vmwait<WP1>();
  __builtin_amdgcn_s_barrier();

  // ---- phase 2: read A-hi(8); issue (t+2).Bq0,Bq1; MFMA Q11 ----
  bf16x8 af2[4][2];
#pragma unroll
  for (int mi = 0; mi < 4; ++mi) { af2[mi][0] = rdA(4 + mi, 0); af2[mi][1] = rdA(4 + mi, 1); }
  if constexpr (ISS123) {
    stage_q(Bt, bn, K, t + 2, 0, Bs, w, lane);
    stage_q(Bt, bn, K, t + 2, 1, Bs, w, lane);
  }
  __builtin_amdgcn_s_barrier();
  __builtin_amdgcn_s_setprio(1);
#pragma unroll
  for (int mi = 0; mi < 4; ++mi) {
    acc[4 + mi][2] = mfma16(af2[mi][0], bfh[0], acc[4 + mi][2]);
    acc[4 + mi][2] = mfma16(af2[mi][1], bfh[1], acc[4 + mi][2]);
  }
  __builtin_amdgcn_s_setprio(0);
  __builtin_amdgcn_s_barrier();

  // ---- phase 3: issue (t+2).Bq2; MFMA Q10; wait WP3 ----
  if constexpr (ISS123) {
    stage_q(Bt, bn, K, t + 2, 2, Bs, w, lane);
  }
  __builtin_amdgcn_s_setprio(1);
#pragma unroll
  for (int mi = 0; mi < 4; ++mi)
#pragma unroll
    for (int ni = 0; ni < 2; ++ni) {
      acc[4 + mi][ni] = mfma16(af2[mi][0], bfl[ni][0], acc[4 + mi][ni]);
      acc[4 + mi][ni] = mfma16(af2[mi][1], bfl[ni][1], acc[4 + mi][ni]);
    }
  __builtin_amdgcn_s_setprio(0);
  if constexpr (!LAST) {
    vmwait<WP3>();
    __builtin_amdgcn_s_barrier();
  }
}

__global__ __launch_bounds__(512, 2) void k_gemm256(
    const u16* __restrict__ A, const u16* __restrict__ Bt,
    const float* __restrict__ scale, u16* __restrict__ C,
    int N, long K) {
  __shared__ u16 As[2][256 * 64];
  __shared__ u16 Bs[2][192 * 64];
  const int tid = threadIdx.x, w = tid >> 6, lane = tid & 63;
  const long bm = (long)blockIdx.y * 256;
  const long bn = (long)blockIdx.x * 192;
  const int nt = (int)(K >> 6);            // K-tiles of 64 (=32 here)

  // prologue (R11 exact, 12 issues): tile0 all 7 + tile1 {Aq0,Aq2,B0,B1,B2};
  // vmcnt(5) -> tile0's 7 landed, tile1's 5 in flight.
  stage_q(A, bm, K, 0, 0, As, w, lane); stage_q(A, bm, K, 0, 2, As, w, lane);
  stage_q(Bt, bn, K, 0, 0, Bs, w, lane); stage_q(Bt, bn, K, 0, 1, Bs, w, lane);
  stage_q(Bt, bn, K, 0, 2, Bs, w, lane);
  stage_q(A, bm, K, 0, 1, As, w, lane); stage_q(A, bm, K, 0, 3, As, w, lane);
  stage_q(A, bm, K, 1, 0, As, w, lane); stage_q(A, bm, K, 1, 2, As, w, lane);
  stage_q(Bt, bn, K, 1, 0, Bs, w, lane); stage_q(Bt, bn, K, 1, 1, Bs, w, lane);
  stage_q(Bt, bn, K, 1, 2, Bs, w, lane);
  vmwait<5>();
  __builtin_amdgcn_s_barrier();

  f32x4 acc[8][3] = {};
  int t = 0;
  for (; t < nt - 2; ++t)
    kstep256<9, 5, true, true, false>(t, A, Bt, K, bm, bn, As, Bs, acc, w, lane);
  kstep256<7, 0, true, false, false>(nt - 2, A, Bt, K, bm, bn, As, Bs, acc, w, lane);
  kstep256<0, 0, false, false, true>(nt - 1, A, Bt, K, bm, bn, As, Bs, acc, w, lane);

  const int l15 = lane & 15, quad = lane >> 4;
  const int wm = (w & 1) * 128, wn = (w >> 1) * 48;
#pragma unroll
  for (int ni = 0; ni < 3; ++ni) {
    const long col = bn + wn + ni * 16 + l15;
    const float sc = scale[col];
#pragma unroll
    for (int mi = 0; mi < 8; ++mi) {
      const long row0 = bm + wm + mi * 16 + quad * 4;
#pragma unroll
      for (int r = 0; r < 4; ++r)
        C[(row0 + r) * (long)N + col] = f2bf(acc[mi][ni][r] * sc);
    }
  }
}

// ---------------- GEMM 128x256 1-round (proj), counted-vmcnt, f32 out -------
// Grid 8x32 = 256 blocks = 1 round. 512thr, 8 waves of 64x64, acc[4][4].
// LDS 96KB. 2-tile lookahead: cur-buf B reads drain by P1's closing
// barrier, A reads by P2's -> stage (t+2).Bq0..3 in P2, (t+2).Aq0,Aq1 in
// P3 (both write cur buf, regions fully read+drained). End-of-tile
// vmcnt(6): 12 in flight (t+1's 6 + t+2's 6) -> waits exactly t+1's.
template<bool ISS, bool LAST, int WEND>
DEVINL void pstep(int t, const u16* __restrict__ A, const u16* __restrict__ Bt,
                  long K, long bm, long bn,
                  u16 (&As)[2][128 * 64], u16 (&Bs)[2][256 * 64],
                  f32x4 (&acc)[4][4], int w, int lane) {
  const int l15 = lane & 15, quad = lane >> 4;
  const int wm = (w & 1) * 64, wn = (w >> 1) * 64;
  const int buf = t & 1;

  auto rdA = [&](int mi, int kc) -> bf16x8 {
    const int row = wm + mi * 16 + l15;
    const int k0 = kc * 32 + quad * 8;
    return ld8(&As[buf][row * 64 + (k0 ^ ((row & 7) * 8))]);
  };
  auto rdB = [&](int ni, int kc) -> bf16x8 {
    const int row = wn + ni * 16 + l15;
    const int k0 = kc * 32 + quad * 8;
    return ld8(&Bs[buf][row * 64 + (k0 ^ ((row & 7) * 8))]);
  };

  bf16x8 a01[2][2], a23[2][2], b01[2][2], b23[2][2];

  // ---- P0: read a01(4)+b01(4); MFMA Q00 ----
#pragma unroll
  for (int mi = 0; mi < 2; ++mi) { a01[mi][0] = rdA(mi, 0); a01[mi][1] = rdA(mi, 1); }
#pragma unroll
  for (int ni = 0; ni < 2; ++ni) { b01[ni][0] = rdB(ni, 0); b01[ni][1] = rdB(ni, 1); }
  __builtin_amdgcn_s_barrier();
  __builtin_amdgcn_s_setprio(1);
#pragma unroll
  for (int mi = 0; mi < 2; ++mi)
#pragma unroll
    for (int ni = 0; ni < 2; ++ni) {
      acc[mi][ni] = mfma16(a01[mi][0], b01[ni][0], acc[mi][ni]);
      acc[mi][ni] = mfma16(a01[mi][1], b01[ni][1], acc[mi][ni]);
    }
  __builtin_amdgcn_s_setprio(0);
  __builtin_amdgcn_s_barrier();

  // ---- P1: read b23(4); MFMA Q01 ----
#pragma unroll
  for (int ni = 0; ni < 2; ++ni) { b23[ni][0] = rdB(2 + ni, 0); b23[ni][1] = rdB(2 + ni, 1); }
  __builtin_amdgcn_s_barrier();
  __builtin_amdgcn_s_setprio(1);
#pragma unroll
  for (int mi = 0; mi < 2; ++mi)
#pragma unroll
    for (int ni = 0; ni < 2; ++ni) {
      acc[mi][2 + ni] = mfma16(a01[mi][0], b23[ni][0], acc[mi][2 + ni]);
      acc[mi][2 + ni] = mfma16(a01[mi][1], b23[ni][1], acc[mi][2 + ni]);
    }
  __builtin_amdgcn_s_setprio(0);
  __builtin_amdgcn_s_barrier();

  // ---- P2: issue (t+2).Bq0..3 (cur buf; B reads drained @P1 barrier);
  //          read a23(4); MFMA Q11 ----
  if constexpr (ISS) {
    stage_q(Bt, bn, K, t + 2, 0, Bs, w, lane);
    stage_q(Bt, bn, K, t + 2, 1, Bs, w, lane);
    stage_q(Bt, bn, K, t + 2, 2, Bs, w, lane);
    stage_q(Bt, bn, K, t + 2, 3, Bs, w, lane);
  }
#pragma unroll
  for (int mi = 0; mi < 2; ++mi) { a23[mi][0] = rdA(2 + mi, 0); a23[mi][1] = rdA(2 + mi, 1); }
  __builtin_amdgcn_s_barrier();
  __builtin_amdgcn_s_setprio(1);
#pragma unroll
  for (int mi = 0; mi < 2; ++mi)
#pragma unroll
    for (int ni = 0; ni < 2; ++ni) {
      acc[2 + mi][2 + ni] = mfma16(a23[mi][0], b23[ni][0], acc[2 + mi][2 + ni]);
      acc[2 + mi][2 + ni] = mfma16(a23[mi][1], b23[ni][1], acc[2 + mi][2 + ni]);
    }
  __builtin_amdgcn_s_setprio(0);
  __builtin_amdgcn_s_barrier();

  // ---- P3: issue (t+2).Aq0,Aq1 (cur buf; A reads drained @P2 barrier);
  //          MFMA Q10; end-of-tile wait ----
  if constexpr (ISS) {
    stage_q(A, bm, K, t + 2, 0, As, w, lane);
    stage_q(A, bm, K, t + 2, 1, As, w, lane);
  }
  __builtin_amdgcn_s_setprio(1);
#pragma unroll
  for (int mi = 0; mi < 2; ++mi)
#pragma unroll
    for (int ni = 0; ni < 2; ++ni) {
      acc[2 + mi][ni] = mfma16(a23[mi][0], b01[ni][0], acc[2 + mi][ni]);
      acc[2 + mi][ni] = mfma16(a23[mi][1], b01[ni][1], acc[2 + mi][ni]);
    }
  __builtin_amdgcn_s_setprio(0);
  if constexpr (!LAST) {
    vmwait<WEND>();
    __builtin_amdgcn_s_barrier();
  }
}

__global__ __launch_bounds__(512, 2) void k_gemm_proj(
    const u16* __restrict__ A, const u16* __restrict__ Bt,
    const float* __restrict__ scale, float* __restrict__ C,
    int N, long K) {
  __shared__ u16 As[2][128 * 64];
  __shared__ u16 Bs[2][256 * 64];
  const int tid = threadIdx.x, w = tid >> 6, lane = tid & 63;
  const long bm = (long)blockIdx.y * 128;
  const long bn = (long)blockIdx.x * 256;
  const int nt = (int)(K >> 6);

  // prologue: tile0 (6) then tile1 (6); vmcnt(6) -> tile0 landed,
  // tile1's 6 in flight (land by end-of-tile-0 vmcnt(6)).
  stage_q(A, bm, K, 0, 0, As, w, lane); stage_q(A, bm, K, 0, 1, As, w, lane);
  stage_q(Bt, bn, K, 0, 0, Bs, w, lane); stage_q(Bt, bn, K, 0, 1, Bs, w, lane);
  stage_q(Bt, bn, K, 0, 2, Bs, w, lane); stage_q(Bt, bn, K, 0, 3, Bs, w, lane);
  stage_q(A, bm, K, 1, 0, As, w, lane); stage_q(A, bm, K, 1, 1, As, w, lane);
  stage_q(Bt, bn, K, 1, 0, Bs, w, lane); stage_q(Bt, bn, K, 1, 1, Bs, w, lane);
  stage_q(Bt, bn, K, 1, 2, Bs, w, lane); stage_q(Bt, bn, K, 1, 3, Bs, w, lane);
  vmwait<6>();
  __builtin_amdgcn_s_barrier();

  f32x4 acc[4][4] = {};
  int t = 0;
  for (; t < nt - 2; ++t)
    pstep<true, false, 6>(t, A, Bt, K, bm, bn, As, Bs, acc, w, lane);
  pstep<false, false, 0>(nt - 2, A, Bt, K, bm, bn, As, Bs, acc, w, lane);
  pstep<false, true, 0>(nt - 1, A, Bt, K, bm, bn, As, Bs, acc, w, lane);

  const int l15 = lane & 15, quad = lane >> 4;
  const int wm = (w & 1) * 64, wn = (w >> 1) * 64;
#pragma unroll
  for (int ni = 0; ni < 4; ++ni) {
    const long col = bn + wn + ni * 16 + l15;
    const float sc = scale[col];
#pragma unroll
    for (int mi = 0; mi < 4; ++mi) {
      const long row0 = bm + wm + mi * 16 + quad * 4;
#pragma unroll
      for (int r = 0; r < 4; ++r)
        C[(row0 + r) * (long)N + col] = acc[mi][ni][r] * sc;
    }
  }
}

// ---------------- fused l2norm(q,k) + V transpose (disjoint regions) --------
__global__ __launch_bounds__(256) void k_norm_vt(u16* __restrict__ qkv,
                                                 const float* __restrict__ qk_gain,
                                                 u16* __restrict__ vt) {
  const int b = blockIdx.x;
  if (b < 4096) {
    const int token = b;
    const int wave = threadIdx.x >> 6, lane = threadIdx.x & 63;
    const float g = qk_gain[0];
    const float qmul = g * g * 1.44269504f * 0.08838834764f;
    u16* rowp = qkv + (long)token * TC3;
#pragma unroll
    for (int s = 0; s < 8; ++s) {
      const int seg = wave * 8 + s;
      const int isK = seg >> 4;
      const int h = seg & 15;
      u16* ptr = rowp + isK * C_ + h * 128 + lane * 2;
      unsigned pv = *(const unsigned*)ptr;
      float a = bf2f((u16)(pv & 0xffffu));
      float bb = bf2f((u16)(pv >> 16));
      float ss = a * a + bb * bb;
#pragma unroll
      for (int m = 1; m <= 32; m <<= 1) ss += __shfl_xor(ss, m);
      float denom = fmaxf(sqrtf(ss), 1e-12f);
      float f = (isK ? 1.0f : qmul) / denom;
      u16 o0 = f2bf(a * f), o1 = f2bf(bb * f);
      *(unsigned*)ptr = (unsigned)o0 | ((unsigned)o1 << 16);
    }
  } else {
    const int v = b - 4096;
    const int t0 = (v & 31) * 64;
    const int h = (v >> 5) & 15;
    const int bz = v >> 9;
    const int t = threadIdx.x & 63;
    const int d0 = threadIdx.x >> 6;       // 0..3
    const long tokbase = (long)bz * T_;
    const u16* src = qkv + (tokbase + t0 + t) * (long)TC3 + 2 * C_ + h * 128;
    u16* dst = vt + ((long)(bz * 16 + h) * 128) * (long)T_ + t0 + t;
#pragma unroll
    for (int dd = 0; dd < 32; ++dd) {
      const int d = dd * 4 + d0;
      dst[(long)d * T_] = src[d];
    }
  }
}

// ---------------- flash attention (causal), m=0 softmax, 32x32 MFMA ---------
__global__ __launch_bounds__(256, 2) void k_attn(const u16* __restrict__ qkv,
                                                 const u16* __restrict__ vtg,
                                                 u16* __restrict__ y) {
  const int qt = blockIdx.z ? (15 - blockIdx.x) : blockIdx.x;
  const int h  = blockIdx.y;
  const int bz = blockIdx.z;
  const int tid = threadIdx.x, w = tid >> 6, lane = tid & 63;
  const int m31 = lane & 31, hi = lane >> 5;

  __shared__ u16 Ks[2][64 * 128];
  __shared__ u16 Vt[2][128 * 64];

  const long tokbase = (long)bz * T_;
  const int qbase = qt * 128 + w * 32;     // 32 queries per wave
  const u16* vbase = vtg + ((long)(bz * 16 + h) * 128) * (long)T_;
  const u16* kbase = qkv + tokbase * TC3 + C_ + h * 128;

  // Q B-frags (32x32x16: col=lane&31=query, k=d=kc*16+hi*8+i)
  bf16x8 qf[8];
  {
    const u16* qp = qkv + (tokbase + qbase + m31) * (long)TC3 + h * 128 + hi * 8;
#pragma unroll
    for (int kc = 0; kc < 8; ++kc)
      qf[kc] = ld8(qp + kc * 16);
  }

  f32x16 o[4];                             // O^T: d=db*32+crow(reg,hi), q=m31
#pragma unroll
  for (int i = 0; i < 4; ++i)
#pragma unroll
    for (int r = 0; r < 16; ++r) o[i][r] = 0.f;
  f32x4 lacc = {0.f, 0.f, 0.f, 0.f};       // per-lane partial row sums (m==0)

  auto stage = [&](int ktb, int b2) {
#pragma unroll
    for (int j = 0; j < 4; ++j) {
      const int t = w * 4 + j;
      const int p = t * 64 + lane;
      const int r  = p >> 4, ck = p & 15;          // K: row r, chunk ck
      async_cp16(kbase + (long)(ktb + r) * TC3 + ((ck ^ (r & 15)) * 8),
                 &Ks[b2][t * 512]);
      const int d  = p >> 3, cv = p & 7;           // V: row d, chunk cv
      async_cp16(vbase + (long)d * T_ + ktb + ((cv ^ (d & 7)) * 8),
                 &Vt[b2][t * 512]);
    }
  };

  stage(0, 0);
  __syncthreads();                         // drain tile-0 staging
  int b = 0;
  const int ktmax = 2 * qt + 1;

  for (int kt = 0; kt <= ktmax; ++kt) {
    const int ktb = kt * 64;
    if (kt < ktmax) stage(ktb + 64, b ^ 1);

    if (ktb <= qbase + 31) {               // skip fully-masked tiles
      // --- S^T = K.Q^T (32x32x16): C frag key=kb*32+crow, query=m31 ---
      f32x16 sA[2];
      __builtin_amdgcn_s_setprio(1);
#pragma unroll
      for (int kb = 0; kb < 2; ++kb) {
        f32x16 acc;
#pragma unroll
        for (int r = 0; r < 16; ++r) acc[r] = 0.f;
#pragma unroll
        for (int kc = 0; kc < 8; ++kc) {
          bf16x8 kf = ld8(&Ks[b][(kb * 32 + m31) * 128 +
                                 (((2 * kc + hi) ^ (lane & 15)) * 8)]);
          acc = mfma32(kf, qf[kc], acc);
        }
        sA[kb] = acc;
      }
      __builtin_amdgcn_s_setprio(0);

      // --- causal mask (one tile per wave hits this) ---
      if (ktb + 63 > qbase) {
        const int qq = qbase + m31;
#pragma unroll
        for (int kb = 0; kb < 2; ++kb)
#pragma unroll
          for (int r = 0; r < 16; ++r) {
            const int key = ktb + kb * 32 + (r & 3) + 8 * (r >> 2) + 4 * hi;
            if (key > qq) sA[kb][r] = -1e30f;
          }
      }
      // --- m=0 softmax: P = exp2(s), 4-way partial sum chains ---
#pragma unroll
      for (int kb = 0; kb < 2; ++kb)
#pragma unroll
        for (int r = 0; r < 16; ++r) {
          float p = __builtin_amdgcn_exp2f(sA[kb][r]);
          sA[kb][r] = p;
          lacc[r & 3] += p;
        }

      // --- P^T B-frags via cvt_pk + permlane32_swap (pure VALU) ---
      bf16x8 pb[4];
#pragma unroll
      for (int ks = 0; ks < 4; ++ks) {
        const int kb = ks >> 1, j = ks & 1;
        unsigned w0a = cvtpk(sA[kb][8 * j + 0], sA[kb][8 * j + 1]);
        unsigned w1a = cvtpk(sA[kb][8 * j + 2], sA[kb][8 * j + 3]);
        unsigned w0b = cvtpk(sA[kb][8 * j + 4], sA[kb][8 * j + 5]);
        unsigned w1b = cvtpk(sA[kb][8 * j + 6], sA[kb][8 * j + 7]);
        plswap(w0a, w0b);                  // w0a=word0, w0b=word2
        plswap(w1a, w1b);                  // w1a=word1, w1b=word3
        uint4x t; t.x = w0a; t.y = w1a; t.z = w0b; t.w = w1b;
        pb[ks] = __builtin_bit_cast(bf16x8, t);
      }

      // --- O^T += V^T.P^T: A=V^T rows d, k=keys ks*16+hi*8+i ---
      __builtin_amdgcn_s_setprio(1);
#pragma unroll
      for (int db = 0; db < 4; ++db)
#pragma unroll
        for (int ks = 0; ks < 4; ++ks) {
          bf16x8 vf = ld8(&Vt[b][(db * 32 + m31) * 64 +
                                 (((2 * ks + hi) ^ (m31 & 7)) * 8)]);
          o[db] = mfma32(vf, pb[ks], o[db]);
        }
      __builtin_amdgcn_s_setprio(0);
    }

    if (kt < ktmax) __syncthreads();       // drains prefetch + guards buffers
    b ^= 1;
  }

  // --- epilogue: l = sum over both lane halves; write O^T ---
  float lrow = lacc[0] + lacc[1] + lacc[2] + lacc[3];
  lrow += __shfl_xor(lrow, 32);
  const float inv_l = 1.0f / lrow;
  u16* yp = y + (tokbase + qbase + m31) * (long)C_ + h * 128 + 4 * hi;
#pragma unroll
  for (int db = 0; db < 4; ++db)
#pragma unroll
    for (int g = 0; g < 4; ++g) {
      u16x4 pk;
#pragma unroll
      for (int r = 0; r < 4; ++r) pk[r] = f2bf(o[db][g * 4 + r] * inv_l);
      *(u16x4*)(yp + db * 32 + g * 8) = pk;
    }
}

// ---------------------------------------------------------------------------
extern "C" void kernel_launch(void* const* d_in, const int* in_sizes, int n_in,
                              void* d_out, int out_size, void* d_ws, size_t ws_size,
                              hipStream_t stream) {
  const float* x    = (const float*)d_in[0];
  const int*   aw   = (const int*)d_in[1];
  const float* asc  = (const float*)d_in[2];
  const int*   pw   = (const int*)d_in[3];
  const float* psc  = (const float*)d_in[4];
  const float* gain = (const float*)d_in[5];

  char* ws = (char*)d_ws;
  u16* xb  = (u16*)(ws);                         // 16.78 MB (reused as Vt_g)
  u16* wab = (u16*)(ws + 16777216UL);
  u16* wpb = (u16*)(ws + 41943040UL);
  u16* qkv = (u16*)(ws + 50331648UL);
  u16* yb  = (u16*)(ws + 100663296UL);
  u16* vtg = xb;                                 // x_bf16 dead after QKV GEMM

  k_cast_all<<<24576, 256, 0, stream>>>(x, aw, pw, xb, wab, wpb);
  k_gemm256<<<dim3(32, 16), 512, 0, stream>>>(xb, wab, asc, qkv, TC3, (long)C_);
  k_norm_vt<<<5120, 256, 0, stream>>>(qkv, gain, vtg);
  k_attn<<<dim3(16, 16, 2), 256, 0, stream>>>(qkv, vtg, yb);
  k_gemm_proj<<<dim3(8, 32), 512, 0, stream>>>(yb, wpb, psc, (float*)d_out, C_, (long)C_);
}

// Round 11
// 391.636 us; speedup vs baseline: 1.2012x; 1.0133x over previous
//
#include <hip/hip_runtime.h>

// ---------------------------------------------------------------------------
// QKGainAttention on MI355X (gfx950), round 18.
// R17 postmortem: proj counted-vmcnt landed (-19us, 416->397). gemm256
// frozen (130us). New analysis: attn (~72us) is HBM-REFETCH-bound, not
// latency: per (h,bz) the 16 causal q-blocks re-read K/V prefixes = 278MB
// -> 47us floor. All 16 sharers on ONE XCD puts the 512KB K/V set in that
// XCD's 4MB L2 -> ~9x traffic cut. R18: XCD-pinning remap in k_attn only
// (wgid%8=XCD heuristic): lin=bx+16by+256bz; xcd=lin&7; idx=lin>>3;
// g=4xcd+(idx>>4); qt=(idx&32)?15-(idx&15):(idx&15); h=g&15; bz=g>>4.
// Bijective; 4 groups x 512KB = 2MB <= 4MB L2 per XCD; CU slot idx%32 gets
// qt and 15-qt (balanced). Wrong-heuristic risk = perf only. Rest verbatim.
// ---------------------------------------------------------------------------

#define DEVINL __device__ __forceinline__

typedef unsigned short u16;
typedef __bf16 bf16x8 __attribute__((ext_vector_type(8)));
typedef float  f32x4  __attribute__((ext_vector_type(4)));
typedef float  f32x16 __attribute__((ext_vector_type(16)));
typedef short  short8 __attribute__((ext_vector_type(8)));
typedef u16    u16x4  __attribute__((ext_vector_type(4)));
typedef unsigned uint4x __attribute__((ext_vector_type(4)));

static constexpr int T_  = 2048;
static constexpr int C_  = 2048;
static constexpr int TC3 = 6144;   // 3*C

DEVINL u16 f2bf(float f) {
  union { float f; unsigned u; } v; v.f = f;
  unsigned r = v.u + 0x7FFFu + ((v.u >> 16) & 1u);   // RNE
  return (u16)(r >> 16);
}
DEVINL float bf2f(u16 s) {
  union { unsigned u; float f; } v; v.u = ((unsigned)s) << 16;
  return v.f;
}
DEVINL bf16x8 ld8(const u16* p) {
  return __builtin_bit_cast(bf16x8, *(const short8*)p);
}
DEVINL f32x4 mfma16(bf16x8 a, bf16x8 b, f32x4 c) {
  return __builtin_amdgcn_mfma_f32_16x16x32_bf16(a, b, c, 0, 0, 0);
}
DEVINL f32x16 mfma32(bf16x8 a, bf16x8 b, f32x16 c) {
  return __builtin_amdgcn_mfma_f32_32x32x16_bf16(a, b, c, 0, 0, 0);
}
DEVINL void async_cp16(const u16* gp, u16* lp) {
  __builtin_amdgcn_global_load_lds(
      (const __attribute__((address_space(1))) void*)gp,
      (__attribute__((address_space(3))) void*)lp, 16, 0, 0);
}
DEVINL unsigned cvtpk(float lo, float hi) {
  unsigned r;
  asm("v_cvt_pk_bf16_f32 %0, %1, %2" : "=v"(r) : "v"(lo), "v"(hi));
  return r;
}
DEVINL void plswap(unsigned& a, unsigned& b) {
  asm("v_permlane32_swap_b32 %0, %1" : "+v"(a), "+v"(b));
}
template<int N> DEVINL void vmwait() {
  if constexpr (N == 0)      asm volatile("s_waitcnt vmcnt(0)" ::: "memory");
  else if constexpr (N == 5) asm volatile("s_waitcnt vmcnt(5)" ::: "memory");
  else if constexpr (N == 6) asm volatile("s_waitcnt vmcnt(6)" ::: "memory");
  else if constexpr (N == 7) asm volatile("s_waitcnt vmcnt(7)" ::: "memory");
  else if constexpr (N == 9) asm volatile("s_waitcnt vmcnt(9)" ::: "memory");
}

// ---------------- fused dtype casts (3 inputs, one launch) ----------------
__global__ __launch_bounds__(256) void k_cast_all(
    const float* __restrict__ x, const int* __restrict__ aw,
    const int* __restrict__ pw, u16* __restrict__ xb,
    u16* __restrict__ wab, u16* __restrict__ wpb) {
  const int b = blockIdx.x;
  if (b < 8192) {
    long i = (long)(b * 256 + threadIdx.x) * 4;
    float4 v = *(const float4*)(x + i);
    u16x4 o; o.x = f2bf(v.x); o.y = f2bf(v.y); o.z = f2bf(v.z); o.w = f2bf(v.w);
    *(u16x4*)(xb + i) = o;
  } else {
    const int* in; u16* out; int lb;
    if (b < 20480) { in = aw; out = wab; lb = b - 8192; }
    else           { in = pw; out = wpb; lb = b - 20480; }
    long i = (long)(lb * 256 + threadIdx.x) * 4;
    int4 v = *(const int4*)(in + i);
    u16x4 o; o.x = f2bf((float)v.x); o.y = f2bf((float)v.y);
    o.z = f2bf((float)v.z); o.w = f2bf((float)v.w);
    *(u16x4*)(out + i) = o;
  }
}

// ---------------- GEMM 256x192 8-phase counted-vmcnt (QKV) -- R11 ----------
// LDS: [buf][row][k 0..63] bf16, XOR-swizzled: (row,k) at row*64 +
// (k ^ ((row&7)*8)).  Staging unit = 64-row quarter (8KB = 1 gload_lds
// x16B / thread @512thr); linear LDS dest + inverse-swizzled global source.
template<int SZ>
DEVINL void stage_q(const u16* __restrict__ G, long brow, long K, int tt, int qi,
                    u16 (&L)[2][SZ], int w, int lane) {
  const int sr = w * 8 + (lane >> 3);      // row within quarter
  const int sc = lane & 7;                 // 16B chunk
  const long grow = brow + qi * 64 + sr;
  async_cp16(G + grow * K + (long)(tt << 6) + ((sc ^ (sr & 7)) << 3),
             &L[tt & 1][(qi * 64 + w * 8) * 64]);
}

template<int WP1, int WP3, bool ISS0, bool ISS123, bool LAST>
DEVINL void kstep256(int t, const u16* __restrict__ A, const u16* __restrict__ Bt,
                     long K, long bm, long bn,
                     u16 (&As)[2][256 * 64], u16 (&Bs)[2][192 * 64],
                     f32x4 (&acc)[8][3], int w, int lane) {
  const int l15 = lane & 15, quad = lane >> 4;
  const int wm = (w & 1) * 128;
  const int wn = (w >> 1) * 48;
  const int buf = t & 1;

  auto rdA = [&](int mi, int kc) -> bf16x8 {
    const int row = wm + mi * 16 + l15;
    const int k0 = kc * 32 + quad * 8;
    return ld8(&As[buf][row * 64 + (k0 ^ ((row & 7) * 8))]);
  };
  auto rdB = [&](int ni, int kc) -> bf16x8 {
    const int row = wn + ni * 16 + l15;
    const int k0 = kc * 32 + quad * 8;
    return ld8(&Bs[buf][row * 64 + (k0 ^ ((row & 7) * 8))]);
  };

  // ---- phase 0: read A-lo(8) + B-lo(4); issue (t+1).Aq1,Aq3; MFMA Q00 ----
  bf16x8 af[4][2], bfl[2][2];
#pragma unroll
  for (int mi = 0; mi < 4; ++mi) { af[mi][0] = rdA(mi, 0); af[mi][1] = rdA(mi, 1); }
#pragma unroll
  for (int ni = 0; ni < 2; ++ni) { bfl[ni][0] = rdB(ni, 0); bfl[ni][1] = rdB(ni, 1); }
  if constexpr (ISS0) {
    stage_q(A, bm, K, t + 1, 1, As, w, lane);
    stage_q(A, bm, K, t + 1, 3, As, w, lane);
  }
  __builtin_amdgcn_s_barrier();
  __builtin_amdgcn_s_setprio(1);
#pragma unroll
  for (int mi = 0; mi < 4; ++mi)
#pragma unroll
    for (int ni = 0; ni < 2; ++ni) {
      acc[mi][ni] = mfma16(af[mi][0], bfl[ni][0], acc[mi][ni]);
      acc[mi][ni] = mfma16(af[mi][1], bfl[ni][1], acc[mi][ni]);
    }
  __builtin_amdgcn_s_setprio(0);
  __builtin_amdgcn_s_barrier();

  // ---- phase 1: read B-hi(2); issue (t+2).Aq0,Aq2; MFMA Q01; wait WP1 ----
  bf16x8 bfh[2];
  bfh[0] = rdB(2, 0); bfh[1] = rdB(2, 1);
  if constexpr (ISS123) {
    stage_q(A, bm, K, t + 2, 0, As, w, lane);
    stage_q(A, bm, K, t + 2, 2, As, w, lane);
  }
  __builtin_amdgcn_s_barrier();
  __builtin_amdgcn_s_setprio(1);
#pragma unroll
  for (int mi = 0; mi < 4; ++mi) {
    acc[mi][2] = mfma16(af[mi][0], bfh[0], acc[mi][2]);
    acc[mi][2] = mfma16(af[mi][1], bfh[1], acc[mi][2]);
  }
  __builtin_amdgcn_s_setprio(0);
  vmwait<WP1>();
  __builtin_amdgcn_s_barrier();

  // ---- phase 2: read A-hi(8); issue (t+2).Bq0,Bq1; MFMA Q11 ----
  bf16x8 af2[4][2];
#pragma unroll
  for (int mi = 0; mi < 4; ++mi) { af2[mi][0] = rdA(4 + mi, 0); af2[mi][1] = rdA(4 + mi, 1); }
  if constexpr (ISS123) {
    stage_q(Bt, bn, K, t + 2, 0, Bs, w, lane);
    stage_q(Bt, bn, K, t + 2, 1, Bs, w, lane);
  }
  __builtin_amdgcn_s_barrier();
  __builtin_amdgcn_s_setprio(1);
#pragma unroll
  for (int mi = 0; mi < 4; ++mi) {
    acc[4 + mi][2] = mfma16(af2[mi][0], bfh[0], acc[4 + mi][2]);
    acc[4 + mi][2] = mfma16(af2[mi][1], bfh[1], acc[4 + mi][2]);
  }
  __builtin_amdgcn_s_setprio(0);
  __builtin_amdgcn_s_barrier();

  // ---- phase 3: issue (t+2).Bq2; MFMA Q10; wait WP3 ----
  if constexpr (ISS123) {
    stage_q(Bt, bn, K, t + 2, 2, Bs, w, lane);
  }
  __builtin_amdgcn_s_setprio(1);
#pragma unroll
  for (int mi = 0; mi < 4; ++mi)
#pragma unroll
    for (int ni = 0; ni < 2; ++ni) {
      acc[4 + mi][ni] = mfma16(af2[mi][0], bfl[ni][0], acc[4 + mi][ni]);
      acc[4 + mi][ni] = mfma16(af2[mi][1], bfl[ni][1], acc[4 + mi][ni]);
    }
  __builtin_amdgcn_s_setprio(0);
  if constexpr (!LAST) {
    vmwait<WP3>();
    __builtin_amdgcn_s_barrier();
  }
}

__global__ __launch_bounds__(512, 2) void k_gemm256(
    const u16* __restrict__ A, const u16* __restrict__ Bt,
    const float* __restrict__ scale, u16* __restrict__ C,
    int N, long K) {
  __shared__ u16 As[2][256 * 64];
  __shared__ u16 Bs[2][192 * 64];
  const int tid = threadIdx.x, w = tid >> 6, lane = tid & 63;
  const long bm = (long)blockIdx.y * 256;
  const long bn = (long)blockIdx.x * 192;
  const int nt = (int)(K >> 6);            // K-tiles of 64 (=32 here)

  // prologue (R11 exact, 12 issues): tile0 all 7 + tile1 {Aq0,Aq2,B0,B1,B2};
  // vmcnt(5) -> tile0's 7 landed, tile1's 5 in flight.
  stage_q(A, bm, K, 0, 0, As, w, lane); stage_q(A, bm, K, 0, 2, As, w, lane);
  stage_q(Bt, bn, K, 0, 0, Bs, w, lane); stage_q(Bt, bn, K, 0, 1, Bs, w, lane);
  stage_q(Bt, bn, K, 0, 2, Bs, w, lane);
  stage_q(A, bm, K, 0, 1, As, w, lane); stage_q(A, bm, K, 0, 3, As, w, lane);
  stage_q(A, bm, K, 1, 0, As, w, lane); stage_q(A, bm, K, 1, 2, As, w, lane);
  stage_q(Bt, bn, K, 1, 0, Bs, w, lane); stage_q(Bt, bn, K, 1, 1, Bs, w, lane);
  stage_q(Bt, bn, K, 1, 2, Bs, w, lane);
  vmwait<5>();
  __builtin_amdgcn_s_barrier();

  f32x4 acc[8][3] = {};
  int t = 0;
  for (; t < nt - 2; ++t)
    kstep256<9, 5, true, true, false>(t, A, Bt, K, bm, bn, As, Bs, acc, w, lane);
  kstep256<7, 0, true, false, false>(nt - 2, A, Bt, K, bm, bn, As, Bs, acc, w, lane);
  kstep256<0, 0, false, false, true>(nt - 1, A, Bt, K, bm, bn, As, Bs, acc, w, lane);

  const int l15 = lane & 15, quad = lane >> 4;
  const int wm = (w & 1) * 128, wn = (w >> 1) * 48;
#pragma unroll
  for (int ni = 0; ni < 3; ++ni) {
    const long col = bn + wn + ni * 16 + l15;
    const float sc = scale[col];
#pragma unroll
    for (int mi = 0; mi < 8; ++mi) {
      const long row0 = bm + wm + mi * 16 + quad * 4;
#pragma unroll
      for (int r = 0; r < 4; ++r)
        C[(row0 + r) * (long)N + col] = f2bf(acc[mi][ni][r] * sc);
    }
  }
}

// ---------------- GEMM 128x256 1-round (proj), counted-vmcnt, f32 out -------
// Grid 8x32 = 256 blocks = 1 round. 512thr, 8 waves of 64x64, acc[4][4].
// LDS 96KB. 2-tile lookahead: stage (t+2).Bq0..3 in P2, (t+2).Aq0,Aq1 in
// P3; end-of-tile vmcnt(6) lands exactly t+1's 6 quarters.
template<bool ISS, bool LAST, int WEND>
DEVINL void pstep(int t, const u16* __restrict__ A, const u16* __restrict__ Bt,
                  long K, long bm, long bn,
                  u16 (&As)[2][128 * 64], u16 (&Bs)[2][256 * 64],
                  f32x4 (&acc)[4][4], int w, int lane) {
  const int l15 = lane & 15, quad = lane >> 4;
  const int wm = (w & 1) * 64, wn = (w >> 1) * 64;
  const int buf = t & 1;

  auto rdA = [&](int mi, int kc) -> bf16x8 {
    const int row = wm + mi * 16 + l15;
    const int k0 = kc * 32 + quad * 8;
    return ld8(&As[buf][row * 64 + (k0 ^ ((row & 7) * 8))]);
  };
  auto rdB = [&](int ni, int kc) -> bf16x8 {
    const int row = wn + ni * 16 + l15;
    const int k0 = kc * 32 + quad * 8;
    return ld8(&Bs[buf][row * 64 + (k0 ^ ((row & 7) * 8))]);
  };

  bf16x8 a01[2][2], a23[2][2], b01[2][2], b23[2][2];

  // ---- P0: read a01(4)+b01(4); MFMA Q00 ----
#pragma unroll
  for (int mi = 0; mi < 2; ++mi) { a01[mi][0] = rdA(mi, 0); a01[mi][1] = rdA(mi, 1); }
#pragma unroll
  for (int ni = 0; ni < 2; ++ni) { b01[ni][0] = rdB(ni, 0); b01[ni][1] = rdB(ni, 1); }
  __builtin_amdgcn_s_barrier();
  __builtin_amdgcn_s_setprio(1);
#pragma unroll
  for (int mi = 0; mi < 2; ++mi)
#pragma unroll
    for (int ni = 0; ni < 2; ++ni) {
      acc[mi][ni] = mfma16(a01[mi][0], b01[ni][0], acc[mi][ni]);
      acc[mi][ni] = mfma16(a01[mi][1], b01[ni][1], acc[mi][ni]);
    }
  __builtin_amdgcn_s_setprio(0);
  __builtin_amdgcn_s_barrier();

  // ---- P1: read b23(4); MFMA Q01 ----
#pragma unroll
  for (int ni = 0; ni < 2; ++ni) { b23[ni][0] = rdB(2 + ni, 0); b23[ni][1] = rdB(2 + ni, 1); }
  __builtin_amdgcn_s_barrier();
  __builtin_amdgcn_s_setprio(1);
#pragma unroll
  for (int mi = 0; mi < 2; ++mi)
#pragma unroll
    for (int ni = 0; ni < 2; ++ni) {
      acc[mi][2 + ni] = mfma16(a01[mi][0], b23[ni][0], acc[mi][2 + ni]);
      acc[mi][2 + ni] = mfma16(a01[mi][1], b23[ni][1], acc[mi][2 + ni]);
    }
  __builtin_amdgcn_s_setprio(0);
  __builtin_amdgcn_s_barrier();

  // ---- P2: issue (t+2).Bq0..3; read a23(4); MFMA Q11 ----
  if constexpr (ISS) {
    stage_q(Bt, bn, K, t + 2, 0, Bs, w, lane);
    stage_q(Bt, bn, K, t + 2, 1, Bs, w, lane);
    stage_q(Bt, bn, K, t + 2, 2, Bs, w, lane);
    stage_q(Bt, bn, K, t + 2, 3, Bs, w, lane);
  }
#pragma unroll
  for (int mi = 0; mi < 2; ++mi) { a23[mi][0] = rdA(2 + mi, 0); a23[mi][1] = rdA(2 + mi, 1); }
  __builtin_amdgcn_s_barrier();
  __builtin_amdgcn_s_setprio(1);
#pragma unroll
  for (int mi = 0; mi < 2; ++mi)
#pragma unroll
    for (int ni = 0; ni < 2; ++ni) {
      acc[2 + mi][2 + ni] = mfma16(a23[mi][0], b23[ni][0], acc[2 + mi][2 + ni]);
      acc[2 + mi][2 + ni] = mfma16(a23[mi][1], b23[ni][1], acc[2 + mi][2 + ni]);
    }
  __builtin_amdgcn_s_setprio(0);
  __builtin_amdgcn_s_barrier();

  // ---- P3: issue (t+2).Aq0,Aq1; MFMA Q10; end-of-tile wait ----
  if constexpr (ISS) {
    stage_q(A, bm, K, t + 2, 0, As, w, lane);
    stage_q(A, bm, K, t + 2, 1, As, w, lane);
  }
  __builtin_amdgcn_s_setprio(1);
#pragma unroll
  for (int mi = 0; mi < 2; ++mi)
#pragma unroll
    for (int ni = 0; ni < 2; ++ni) {
      acc[2 + mi][ni] = mfma16(a23[mi][0], b01[ni][0], acc[2 + mi][ni]);
      acc[2 + mi][ni] = mfma16(a23[mi][1], b01[ni][1], acc[2 + mi][ni]);
    }
  __builtin_amdgcn_s_setprio(0);
  if constexpr (!LAST) {
    vmwait<WEND>();
    __builtin_amdgcn_s_barrier();
  }
}

__global__ __launch_bounds__(512, 2) void k_gemm_proj(
    const u16* __restrict__ A, const u16* __restrict__ Bt,
    const float* __restrict__ scale, float* __restrict__ C,
    int N, long K) {
  __shared__ u16 As[2][128 * 64];
  __shared__ u16 Bs[2][256 * 64];
  const int tid = threadIdx.x, w = tid >> 6, lane = tid & 63;
  const long bm = (long)blockIdx.y * 128;
  const long bn = (long)blockIdx.x * 256;
  const int nt = (int)(K >> 6);

  // prologue: tile0 (6) then tile1 (6); vmcnt(6) -> tile0 landed.
  stage_q(A, bm, K, 0, 0, As, w, lane); stage_q(A, bm, K, 0, 1, As, w, lane);
  stage_q(Bt, bn, K, 0, 0, Bs, w, lane); stage_q(Bt, bn, K, 0, 1, Bs, w, lane);
  stage_q(Bt, bn, K, 0, 2, Bs, w, lane); stage_q(Bt, bn, K, 0, 3, Bs, w, lane);
  stage_q(A, bm, K, 1, 0, As, w, lane); stage_q(A, bm, K, 1, 1, As, w, lane);
  stage_q(Bt, bn, K, 1, 0, Bs, w, lane); stage_q(Bt, bn, K, 1, 1, Bs, w, lane);
  stage_q(Bt, bn, K, 1, 2, Bs, w, lane); stage_q(Bt, bn, K, 1, 3, Bs, w, lane);
  vmwait<6>();
  __builtin_amdgcn_s_barrier();

  f32x4 acc[4][4] = {};
  int t = 0;
  for (; t < nt - 2; ++t)
    pstep<true, false, 6>(t, A, Bt, K, bm, bn, As, Bs, acc, w, lane);
  pstep<false, false, 0>(nt - 2, A, Bt, K, bm, bn, As, Bs, acc, w, lane);
  pstep<false, true, 0>(nt - 1, A, Bt, K, bm, bn, As, Bs, acc, w, lane);

  const int l15 = lane & 15, quad = lane >> 4;
  const int wm = (w & 1) * 64, wn = (w >> 1) * 64;
#pragma unroll
  for (int ni = 0; ni < 4; ++ni) {
    const long col = bn + wn + ni * 16 + l15;
    const float sc = scale[col];
#pragma unroll
    for (int mi = 0; mi < 4; ++mi) {
      const long row0 = bm + wm + mi * 16 + quad * 4;
#pragma unroll
      for (int r = 0; r < 4; ++r)
        C[(row0 + r) * (long)N + col] = acc[mi][ni][r] * sc;
    }
  }
}

// ---------------- fused l2norm(q,k) + V transpose (disjoint regions) --------
__global__ __launch_bounds__(256) void k_norm_vt(u16* __restrict__ qkv,
                                                 const float* __restrict__ qk_gain,
                                                 u16* __restrict__ vt) {
  const int b = blockIdx.x;
  if (b < 4096) {
    const int token = b;
    const int wave = threadIdx.x >> 6, lane = threadIdx.x & 63;
    const float g = qk_gain[0];
    const float qmul = g * g * 1.44269504f * 0.08838834764f;
    u16* rowp = qkv + (long)token * TC3;
#pragma unroll
    for (int s = 0; s < 8; ++s) {
      const int seg = wave * 8 + s;
      const int isK = seg >> 4;
      const int h = seg & 15;
      u16* ptr = rowp + isK * C_ + h * 128 + lane * 2;
      unsigned pv = *(const unsigned*)ptr;
      float a = bf2f((u16)(pv & 0xffffu));
      float bb = bf2f((u16)(pv >> 16));
      float ss = a * a + bb * bb;
#pragma unroll
      for (int m = 1; m <= 32; m <<= 1) ss += __shfl_xor(ss, m);
      float denom = fmaxf(sqrtf(ss), 1e-12f);
      float f = (isK ? 1.0f : qmul) / denom;
      u16 o0 = f2bf(a * f), o1 = f2bf(bb * f);
      *(unsigned*)ptr = (unsigned)o0 | ((unsigned)o1 << 16);
    }
  } else {
    const int v = b - 4096;
    const int t0 = (v & 31) * 64;
    const int h = (v >> 5) & 15;
    const int bz = v >> 9;
    const int t = threadIdx.x & 63;
    const int d0 = threadIdx.x >> 6;       // 0..3
    const long tokbase = (long)bz * T_;
    const u16* src = qkv + (tokbase + t0 + t) * (long)TC3 + 2 * C_ + h * 128;
    u16* dst = vt + ((long)(bz * 16 + h) * 128) * (long)T_ + t0 + t;
#pragma unroll
    for (int dd = 0; dd < 32; ++dd) {
      const int d = dd * 4 + d0;
      dst[(long)d * T_] = src[d];
    }
  }
}

// ---------------- flash attention (causal), m=0 softmax, XCD-pinned ---------
// All 16 q-blocks of one (h,bz) share its 512KB K/V panel. Pin them to one
// XCD (wgid%8 heuristic) so the panel lives in that XCD's 4MB L2:
// lin=bx+16by+256bz; xcd=lin&7; idx=lin>>3; g=4xcd+(idx>>4);
// qt=(idx&32)?15-(idx&15):(idx&15); h=g&15; bz=g>>4. Bijective; 4 groups
// (2MB) per XCD; CU slot idx%32 gets qt and 15-qt (balanced).
__global__ __launch_bounds__(256, 2) void k_attn(const u16* __restrict__ qkv,
                                                 const u16* __restrict__ vtg,
                                                 u16* __restrict__ y) {
  const int lin = blockIdx.x + 16 * blockIdx.y + 256 * blockIdx.z;
  const int xcd = lin & 7;
  const int idx = lin >> 3;                // 0..63
  const int g   = xcd * 4 + (idx >> 4);    // 0..31: (h,bz) group
  const int qr  = idx & 15;
  const int qt  = (idx & 32) ? (15 - qr) : qr;
  const int h   = g & 15;
  const int bz  = g >> 4;
  const int tid = threadIdx.x, w = tid >> 6, lane = tid & 63;
  const int m31 = lane & 31, hi = lane >> 5;

  __shared__ u16 Ks[2][64 * 128];
  __shared__ u16 Vt[2][128 * 64];

  const long tokbase = (long)bz * T_;
  const int qbase = qt * 128 + w * 32;     // 32 queries per wave
  const u16* vbase = vtg + ((long)(bz * 16 + h) * 128) * (long)T_;
  const u16* kbase = qkv + tokbase * TC3 + C_ + h * 128;

  // Q B-frags (32x32x16: col=lane&31=query, k=d=kc*16+hi*8+i)
  bf16x8 qf[8];
  {
    const u16* qp = qkv + (tokbase + qbase + m31) * (long)TC3 + h * 128 + hi * 8;
#pragma unroll
    for (int kc = 0; kc < 8; ++kc)
      qf[kc] = ld8(qp + kc * 16);
  }

  f32x16 o[4];                             // O^T: d=db*32+crow(reg,hi), q=m31
#pragma unroll
  for (int i = 0; i < 4; ++i)
#pragma unroll
    for (int r = 0; r < 16; ++r) o[i][r] = 0.f;
  f32x4 lacc = {0.f, 0.f, 0.f, 0.f};       // per-lane partial row sums (m==0)

  auto stage = [&](int ktb, int b2) {
#pragma unroll
    for (int j = 0; j < 4; ++j) {
      const int t = w * 4 + j;
      const int p = t * 64 + lane;
      const int r  = p >> 4, ck = p & 15;          // K: row r, chunk ck
      async_cp16(kbase + (long)(ktb + r) * TC3 + ((ck ^ (r & 15)) * 8),
                 &Ks[b2][t * 512]);
      const int d  = p >> 3, cv = p & 7;           // V: row d, chunk cv
      async_cp16(vbase + (long)d * T_ + ktb + ((cv ^ (d & 7)) * 8),
                 &Vt[b2][t * 512]);
    }
  };

  stage(0, 0);
  __syncthreads();                         // drain tile-0 staging
  int b = 0;
  const int ktmax = 2 * qt + 1;

  for (int kt = 0; kt <= ktmax; ++kt) {
    const int ktb = kt * 64;
    if (kt < ktmax) stage(ktb + 64, b ^ 1);

    if (ktb <= qbase + 31) {               // skip fully-masked tiles
      // --- S^T = K.Q^T (32x32x16): C frag key=kb*32+crow, query=m31 ---
      f32x16 sA[2];
      __builtin_amdgcn_s_setprio(1);
#pragma unroll
      for (int kb = 0; kb < 2; ++kb) {
        f32x16 acc;
#pragma unroll
        for (int r = 0; r < 16; ++r) acc[r] = 0.f;
#pragma unroll
        for (int kc = 0; kc < 8; ++kc) {
          bf16x8 kf = ld8(&Ks[b][(kb * 32 + m31) * 128 +
                                 (((2 * kc + hi) ^ (lane & 15)) * 8)]);
          acc = mfma32(kf, qf[kc], acc);
        }
        sA[kb] = acc;
      }
      __builtin_amdgcn_s_setprio(0);

      // --- causal mask (one tile per wave hits this) ---
      if (ktb + 63 > qbase) {
        const int qq = qbase + m31;
#pragma unroll
        for (int kb = 0; kb < 2; ++kb)
#pragma unroll
          for (int r = 0; r < 16; ++r) {
            const int key = ktb + kb * 32 + (r & 3) + 8 * (r >> 2) + 4 * hi;
            if (key > qq) sA[kb][r] = -1e30f;
          }
      }
      // --- m=0 softmax: P = exp2(s), 4-way partial sum chains ---
#pragma unroll
      for (int kb = 0; kb < 2; ++kb)
#pragma unroll
        for (int r = 0; r < 16; ++r) {
          float p = __builtin_amdgcn_exp2f(sA[kb][r]);
          sA[kb][r] = p;
          lacc[r & 3] += p;
        }

      // --- P^T B-frags via cvt_pk + permlane32_swap (pure VALU) ---
      bf16x8 pb[4];
#pragma unroll
      for (int ks = 0; ks < 4; ++ks) {
        const int kb = ks >> 1, j = ks & 1;
        unsigned w0a = cvtpk(sA[kb][8 * j + 0], sA[kb][8 * j + 1]);
        unsigned w1a = cvtpk(sA[kb][8 * j + 2], sA[kb][8 * j + 3]);
        unsigned w0b = cvtpk(sA[kb][8 * j + 4], sA[kb][8 * j + 5]);
        unsigned w1b = cvtpk(sA[kb][8 * j + 6], sA[kb][8 * j + 7]);
        plswap(w0a, w0b);                  // w0a=word0, w0b=word2
        plswap(w1a, w1b);                  // w1a=word1, w1b=word3
        uint4x t; t.x = w0a; t.y = w1a; t.z = w0b; t.w = w1b;
        pb[ks] = __builtin_bit_cast(bf16x8, t);
      }

      // --- O^T += V^T.P^T: A=V^T rows d, k=keys ks*16+hi*8+i ---
      __builtin_amdgcn_s_setprio(1);
#pragma unroll
      for (int db = 0; db < 4; ++db)
#pragma unroll
        for (int ks = 0; ks < 4; ++ks) {
          bf16x8 vf = ld8(&Vt[b][(db * 32 + m31) * 64 +
                                 (((2 * ks + hi) ^ (m31 & 7)) * 8)]);
          o[db] = mfma32(vf, pb[ks], o[db]);
        }
      __builtin_amdgcn_s_setprio(0);
    }

    if (kt < ktmax) __syncthreads();       // drains prefetch + guards buffers
    b ^= 1;
  }

  // --- epilogue: l = sum over both lane halves; write O^T ---
  float lrow = lacc[0] + lacc[1] + lacc[2] + lacc[3];
  lrow += __shfl_xor(lrow, 32);
  const float inv_l = 1.0f / lrow;
  u16* yp = y + (tokbase + qbase + m31) * (long)C_ + h * 128 + 4 * hi;
#pragma unroll
  for (int db = 0; db < 4; ++db)
#pragma unroll
    for (int g2 = 0; g2 < 4; ++g2) {
      u16x4 pk;
#pragma unroll
      for (int r = 0; r < 4; ++r) pk[r] = f2bf(o[db][g2 * 4 + r] * inv_l);
      *(u16x4*)(yp + db * 32 + g2 * 8) = pk;
    }
}

// ---------------------------------------------------------------------------
extern "C" void kernel_launch(void* const* d_in, const int* in_sizes, int n_in,
                              void* d_out, int out_size, void* d_ws, size_t ws_size,
                              hipStream_t stream) {
  const float* x    = (const float*)d_in[0];
  const int*   aw   = (const int*)d_in[1];
  const float* asc  = (const float*)d_in[2];
  const int*   pw   = (const int*)d_in[3];
  const float* psc  = (const float*)d_in[4];
  const float* gain = (const float*)d_in[5];

  char* ws = (char*)d_ws;
  u16* xb  = (u16*)(ws);                         // 16.78 MB (reused as Vt_g)
  u16* wab = (u16*)(ws + 16777216UL);
  u16* wpb = (u16*)(ws + 41943040UL);
  u16* qkv = (u16*)(ws + 50331648UL);
  u16* yb  = (u16*)(ws + 100663296UL);
  u16* vtg = xb;                                 // x_bf16 dead after QKV GEMM

  k_cast_all<<<24576, 256, 0, stream>>>(x, aw, pw, xb, wab, wpb);
  k_gemm256<<<dim3(32, 16), 512, 0, stream>>>(xb, wab, asc, qkv, TC3, (long)C_);
  k_norm_vt<<<5120, 256, 0, stream>>>(qkv, gain, vtg);
  k_attn<<<dim3(16, 16, 2), 256, 0, stream>>>(qkv, vtg, yb);
  k_gemm_proj<<<dim3(8, 32), 512, 0, stream>>>(yb, wpb, psc, (float*)d_out, C_, (long)C_);
}

// Round 12
// 386.700 us; speedup vs baseline: 1.2165x; 1.0128x over previous
//
#include <hip/hip_runtime.h>

// ---------------------------------------------------------------------------
// QKGainAttention on MI355X (gfx950), round 19.
// R18 postmortem: XCD-pin gave only -5us -> K/V (16MB total) was already
// L3-resident; attn is latency-bound, leave it. New lever: BARRIER COUNT.
// R11's gemm256 pays 7-8 s_barrier per K-tile (48 mfma16) but the minimal
// correctness ledger needs only 3: end-P0 (guards P1's (t+2).Aq0/Aq2 stages
// into cur buf -- regions last read by P0 A-lo), vmcnt(9)+end-P1 (guards
// A-hi data AND P2/P3's (t+2).B stages -- B last read by P1 B-hi), and
// vmcnt(5)+end-tile. Pre-MFMA barriers + end-P2 deleted (4-5/tile); waves
// may now slip phases (overlap instead of lockstep). Proj likewise 7 -> 3
// (end-P1 before B-stages, end-P2 before A-stages, vmcnt(6)+end-tile).
// Issue order, wait counts, MFMA order unchanged = bit-identical numerics.
// Casts/norm_vt/attn R18-verbatim.
// ---------------------------------------------------------------------------

#define DEVINL __device__ __forceinline__

typedef unsigned short u16;
typedef __bf16 bf16x8 __attribute__((ext_vector_type(8)));
typedef float  f32x4  __attribute__((ext_vector_type(4)));
typedef float  f32x16 __attribute__((ext_vector_type(16)));
typedef short  short8 __attribute__((ext_vector_type(8)));
typedef u16    u16x4  __attribute__((ext_vector_type(4)));
typedef unsigned uint4x __attribute__((ext_vector_type(4)));

static constexpr int T_  = 2048;
static constexpr int C_  = 2048;
static constexpr int TC3 = 6144;   // 3*C

DEVINL u16 f2bf(float f) {
  union { float f; unsigned u; } v; v.f = f;
  unsigned r = v.u + 0x7FFFu + ((v.u >> 16) & 1u);   // RNE
  return (u16)(r >> 16);
}
DEVINL float bf2f(u16 s) {
  union { unsigned u; float f; } v; v.u = ((unsigned)s) << 16;
  return v.f;
}
DEVINL bf16x8 ld8(const u16* p) {
  return __builtin_bit_cast(bf16x8, *(const short8*)p);
}
DEVINL f32x4 mfma16(bf16x8 a, bf16x8 b, f32x4 c) {
  return __builtin_amdgcn_mfma_f32_16x16x32_bf16(a, b, c, 0, 0, 0);
}
DEVINL f32x16 mfma32(bf16x8 a, bf16x8 b, f32x16 c) {
  return __builtin_amdgcn_mfma_f32_32x32x16_bf16(a, b, c, 0, 0, 0);
}
DEVINL void async_cp16(const u16* gp, u16* lp) {
  __builtin_amdgcn_global_load_lds(
      (const __attribute__((address_space(1))) void*)gp,
      (__attribute__((address_space(3))) void*)lp, 16, 0, 0);
}
DEVINL unsigned cvtpk(float lo, float hi) {
  unsigned r;
  asm("v_cvt_pk_bf16_f32 %0, %1, %2" : "=v"(r) : "v"(lo), "v"(hi));
  return r;
}
DEVINL void plswap(unsigned& a, unsigned& b) {
  asm("v_permlane32_swap_b32 %0, %1" : "+v"(a), "+v"(b));
}
template<int N> DEVINL void vmwait() {
  if constexpr (N == 0)      asm volatile("s_waitcnt vmcnt(0)" ::: "memory");
  else if constexpr (N == 5) asm volatile("s_waitcnt vmcnt(5)" ::: "memory");
  else if constexpr (N == 6) asm volatile("s_waitcnt vmcnt(6)" ::: "memory");
  else if constexpr (N == 7) asm volatile("s_waitcnt vmcnt(7)" ::: "memory");
  else if constexpr (N == 9) asm volatile("s_waitcnt vmcnt(9)" ::: "memory");
}

// ---------------- fused dtype casts (3 inputs, one launch) ----------------
__global__ __launch_bounds__(256) void k_cast_all(
    const float* __restrict__ x, const int* __restrict__ aw,
    const int* __restrict__ pw, u16* __restrict__ xb,
    u16* __restrict__ wab, u16* __restrict__ wpb) {
  const int b = blockIdx.x;
  if (b < 8192) {
    long i = (long)(b * 256 + threadIdx.x) * 4;
    float4 v = *(const float4*)(x + i);
    u16x4 o; o.x = f2bf(v.x); o.y = f2bf(v.y); o.z = f2bf(v.z); o.w = f2bf(v.w);
    *(u16x4*)(xb + i) = o;
  } else {
    const int* in; u16* out; int lb;
    if (b < 20480) { in = aw; out = wab; lb = b - 8192; }
    else           { in = pw; out = wpb; lb = b - 20480; }
    long i = (long)(lb * 256 + threadIdx.x) * 4;
    int4 v = *(const int4*)(in + i);
    u16x4 o; o.x = f2bf((float)v.x); o.y = f2bf((float)v.y);
    o.z = f2bf((float)v.z); o.w = f2bf((float)v.w);
    *(u16x4*)(out + i) = o;
  }
}

// ---------------- GEMM 256x192, counted-vmcnt, minimal barriers (QKV) -------
// LDS: [buf][row][k 0..63] bf16, XOR-swizzled: (row,k) at row*64 +
// (k ^ ((row&7)*8)).  Staging unit = 64-row quarter (8KB = 1 gload_lds
// x16B / thread @512thr); linear LDS dest + inverse-swizzled global source.
template<int SZ>
DEVINL void stage_q(const u16* __restrict__ G, long brow, long K, int tt, int qi,
                    u16 (&L)[2][SZ], int w, int lane) {
  const int sr = w * 8 + (lane >> 3);      // row within quarter
  const int sc = lane & 7;                 // 16B chunk
  const long grow = brow + qi * 64 + sr;
  async_cp16(G + grow * K + (long)(tt << 6) + ((sc ^ (sr & 7)) << 3),
             &L[tt & 1][(qi * 64 + w * 8) * 64]);
}

// Barrier ledger (3/tile): B1 end-P0 guards P1's (t+2).Aq0/Aq2 stages (those
// rows last read by P0 A-lo, consumed by Q00 before B1). B2 = vmcnt(WP1)+
// barrier end-P1: A-hi data landed for P2 reads AND all B reads (B-lo P0,
// B-hi P1) retired before P2/P3 B stages. B3 = vmcnt(WP3)+barrier end-tile.
template<int WP1, int WP3, bool ISS0, bool ISS123, bool LAST>
DEVINL void kstep256(int t, const u16* __restrict__ A, const u16* __restrict__ Bt,
                     long K, long bm, long bn,
                     u16 (&As)[2][256 * 64], u16 (&Bs)[2][192 * 64],
                     f32x4 (&acc)[8][3], int w, int lane) {
  const int l15 = lane & 15, quad = lane >> 4;
  const int wm = (w & 1) * 128;
  const int wn = (w >> 1) * 48;
  const int buf = t & 1;

  auto rdA = [&](int mi, int kc) -> bf16x8 {
    const int row = wm + mi * 16 + l15;
    const int k0 = kc * 32 + quad * 8;
    return ld8(&As[buf][row * 64 + (k0 ^ ((row & 7) * 8))]);
  };
  auto rdB = [&](int ni, int kc) -> bf16x8 {
    const int row = wn + ni * 16 + l15;
    const int k0 = kc * 32 + quad * 8;
    return ld8(&Bs[buf][row * 64 + (k0 ^ ((row & 7) * 8))]);
  };

  // ---- P0: read A-lo(8) + B-lo(4); issue (t+1).Aq1,Aq3; MFMA Q00; B1 ----
  bf16x8 af[4][2], bfl[2][2];
#pragma unroll
  for (int mi = 0; mi < 4; ++mi) { af[mi][0] = rdA(mi, 0); af[mi][1] = rdA(mi, 1); }
#pragma unroll
  for (int ni = 0; ni < 2; ++ni) { bfl[ni][0] = rdB(ni, 0); bfl[ni][1] = rdB(ni, 1); }
  if constexpr (ISS0) {
    stage_q(A, bm, K, t + 1, 1, As, w, lane);
    stage_q(A, bm, K, t + 1, 3, As, w, lane);
  }
  __builtin_amdgcn_s_setprio(1);
#pragma unroll
  for (int mi = 0; mi < 4; ++mi)
#pragma unroll
    for (int ni = 0; ni < 2; ++ni) {
      acc[mi][ni] = mfma16(af[mi][0], bfl[ni][0], acc[mi][ni]);
      acc[mi][ni] = mfma16(af[mi][1], bfl[ni][1], acc[mi][ni]);
    }
  __builtin_amdgcn_s_setprio(0);
  __builtin_amdgcn_s_barrier();            // B1

  // ---- P1: read B-hi(2); issue (t+2).Aq0,Aq2 (cur buf, safe after B1);
  //          MFMA Q01; vmcnt(WP1); B2 ----
  bf16x8 bfh[2];
  bfh[0] = rdB(2, 0); bfh[1] = rdB(2, 1);
  if constexpr (ISS123) {
    stage_q(A, bm, K, t + 2, 0, As, w, lane);
    stage_q(A, bm, K, t + 2, 2, As, w, lane);
  }
  __builtin_amdgcn_s_setprio(1);
#pragma unroll
  for (int mi = 0; mi < 4; ++mi) {
    acc[mi][2] = mfma16(af[mi][0], bfh[0], acc[mi][2]);
    acc[mi][2] = mfma16(af[mi][1], bfh[1], acc[mi][2]);
  }
  __builtin_amdgcn_s_setprio(0);
  vmwait<WP1>();
  __builtin_amdgcn_s_barrier();            // B2

  // ---- P2: read A-hi(8); issue (t+2).Bq0,Bq1 (safe after B2); MFMA Q11 ----
  bf16x8 af2[4][2];
#pragma unroll
  for (int mi = 0; mi < 4; ++mi) { af2[mi][0] = rdA(4 + mi, 0); af2[mi][1] = rdA(4 + mi, 1); }
  if constexpr (ISS123) {
    stage_q(Bt, bn, K, t + 2, 0, Bs, w, lane);
    stage_q(Bt, bn, K, t + 2, 1, Bs, w, lane);
  }
  __builtin_amdgcn_s_setprio(1);
#pragma unroll
  for (int mi = 0; mi < 4; ++mi) {
    acc[4 + mi][2] = mfma16(af2[mi][0], bfh[0], acc[4 + mi][2]);
    acc[4 + mi][2] = mfma16(af2[mi][1], bfh[1], acc[4 + mi][2]);
  }
  __builtin_amdgcn_s_setprio(0);

  // ---- P3: issue (t+2).Bq2; MFMA Q10; vmcnt(WP3); B3 ----
  if constexpr (ISS123) {
    stage_q(Bt, bn, K, t + 2, 2, Bs, w, lane);
  }
  __builtin_amdgcn_s_setprio(1);
#pragma unroll
  for (int mi = 0; mi < 4; ++mi)
#pragma unroll
    for (int ni = 0; ni < 2; ++ni) {
      acc[4 + mi][ni] = mfma16(af2[mi][0], bfl[ni][0], acc[4 + mi][ni]);
      acc[4 + mi][ni] = mfma16(af2[mi][1], bfl[ni][1], acc[4 + mi][ni]);
    }
  __builtin_amdgcn_s_setprio(0);
  if constexpr (!LAST) {
    vmwait<WP3>();
    __builtin_amdgcn_s_barrier();          // B3
  }
}

__global__ __launch_bounds__(512, 2) void k_gemm256(
    const u16* __restrict__ A, const u16* __restrict__ Bt,
    const float* __restrict__ scale, u16* __restrict__ C,
    int N, long K) {
  __shared__ u16 As[2][256 * 64];
  __shared__ u16 Bs[2][192 * 64];
  const int tid = threadIdx.x, w = tid >> 6, lane = tid & 63;
  const long bm = (long)blockIdx.y * 256;
  const long bn = (long)blockIdx.x * 192;
  const int nt = (int)(K >> 6);            // K-tiles of 64 (=32 here)

  // prologue (R11 exact, 12 issues): tile0 all 7 + tile1 {Aq0,Aq2,B0,B1,B2};
  // vmcnt(5) -> tile0's 7 landed, tile1's 5 in flight.
  stage_q(A, bm, K, 0, 0, As, w, lane); stage_q(A, bm, K, 0, 2, As, w, lane);
  stage_q(Bt, bn, K, 0, 0, Bs, w, lane); stage_q(Bt, bn, K, 0, 1, Bs, w, lane);
  stage_q(Bt, bn, K, 0, 2, Bs, w, lane);
  stage_q(A, bm, K, 0, 1, As, w, lane); stage_q(A, bm, K, 0, 3, As, w, lane);
  stage_q(A, bm, K, 1, 0, As, w, lane); stage_q(A, bm, K, 1, 2, As, w, lane);
  stage_q(Bt, bn, K, 1, 0, Bs, w, lane); stage_q(Bt, bn, K, 1, 1, Bs, w, lane);
  stage_q(Bt, bn, K, 1, 2, Bs, w, lane);
  vmwait<5>();
  __builtin_amdgcn_s_barrier();

  f32x4 acc[8][3] = {};
  int t = 0;
  for (; t < nt - 2; ++t)
    kstep256<9, 5, true, true, false>(t, A, Bt, K, bm, bn, As, Bs, acc, w, lane);
  kstep256<7, 0, true, false, false>(nt - 2, A, Bt, K, bm, bn, As, Bs, acc, w, lane);
  kstep256<0, 0, false, false, true>(nt - 1, A, Bt, K, bm, bn, As, Bs, acc, w, lane);

  const int l15 = lane & 15, quad = lane >> 4;
  const int wm = (w & 1) * 128, wn = (w >> 1) * 48;
#pragma unroll
  for (int ni = 0; ni < 3; ++ni) {
    const long col = bn + wn + ni * 16 + l15;
    const float sc = scale[col];
#pragma unroll
    for (int mi = 0; mi < 8; ++mi) {
      const long row0 = bm + wm + mi * 16 + quad * 4;
#pragma unroll
      for (int r = 0; r < 4; ++r)
        C[(row0 + r) * (long)N + col] = f2bf(acc[mi][ni][r] * sc);
    }
  }
}

// ---------------- GEMM 128x256 1-round (proj), minimal barriers, f32 out ----
// Barrier ledger (3/tile): BA end-P1 (all B reads retired -> P2 B-stages
// safe), BB end-P2 (all A reads retired -> P3 A-stages safe), vmcnt(6)+
// barrier end-tile (t+1's 6 quarters landed; 12 in flight max).
template<bool ISS, bool LAST, int WEND>
DEVINL void pstep(int t, const u16* __restrict__ A, const u16* __restrict__ Bt,
                  long K, long bm, long bn,
                  u16 (&As)[2][128 * 64], u16 (&Bs)[2][256 * 64],
                  f32x4 (&acc)[4][4], int w, int lane) {
  const int l15 = lane & 15, quad = lane >> 4;
  const int wm = (w & 1) * 64, wn = (w >> 1) * 64;
  const int buf = t & 1;

  auto rdA = [&](int mi, int kc) -> bf16x8 {
    const int row = wm + mi * 16 + l15;
    const int k0 = kc * 32 + quad * 8;
    return ld8(&As[buf][row * 64 + (k0 ^ ((row & 7) * 8))]);
  };
  auto rdB = [&](int ni, int kc) -> bf16x8 {
    const int row = wn + ni * 16 + l15;
    const int k0 = kc * 32 + quad * 8;
    return ld8(&Bs[buf][row * 64 + (k0 ^ ((row & 7) * 8))]);
  };

  bf16x8 a01[2][2], a23[2][2], b01[2][2], b23[2][2];

  // ---- P0: read a01(4)+b01(4); MFMA Q00 ----
#pragma unroll
  for (int mi = 0; mi < 2; ++mi) { a01[mi][0] = rdA(mi, 0); a01[mi][1] = rdA(mi, 1); }
#pragma unroll
  for (int ni = 0; ni < 2; ++ni) { b01[ni][0] = rdB(ni, 0); b01[ni][1] = rdB(ni, 1); }
  __builtin_amdgcn_s_setprio(1);
#pragma unroll
  for (int mi = 0; mi < 2; ++mi)
#pragma unroll
    for (int ni = 0; ni < 2; ++ni) {
      acc[mi][ni] = mfma16(a01[mi][0], b01[ni][0], acc[mi][ni]);
      acc[mi][ni] = mfma16(a01[mi][1], b01[ni][1], acc[mi][ni]);
    }
  __builtin_amdgcn_s_setprio(0);

  // ---- P1: read b23(4); MFMA Q01; BA ----
#pragma unroll
  for (int ni = 0; ni < 2; ++ni) { b23[ni][0] = rdB(2 + ni, 0); b23[ni][1] = rdB(2 + ni, 1); }
  __builtin_amdgcn_s_setprio(1);
#pragma unroll
  for (int mi = 0; mi < 2; ++mi)
#pragma unroll
    for (int ni = 0; ni < 2; ++ni) {
      acc[mi][2 + ni] = mfma16(a01[mi][0], b23[ni][0], acc[mi][2 + ni]);
      acc[mi][2 + ni] = mfma16(a01[mi][1], b23[ni][1], acc[mi][2 + ni]);
    }
  __builtin_amdgcn_s_setprio(0);
  __builtin_amdgcn_s_barrier();            // BA

  // ---- P2: issue (t+2).Bq0..3 (safe after BA); read a23(4); MFMA Q11; BB --
  if constexpr (ISS) {
    stage_q(Bt, bn, K, t + 2, 0, Bs, w, lane);
    stage_q(Bt, bn, K, t + 2, 1, Bs, w, lane);
    stage_q(Bt, bn, K, t + 2, 2, Bs, w, lane);
    stage_q(Bt, bn, K, t + 2, 3, Bs, w, lane);
  }
#pragma unroll
  for (int mi = 0; mi < 2; ++mi) { a23[mi][0] = rdA(2 + mi, 0); a23[mi][1] = rdA(2 + mi, 1); }
  __builtin_amdgcn_s_setprio(1);
#pragma unroll
  for (int mi = 0; mi < 2; ++mi)
#pragma unroll
    for (int ni = 0; ni < 2; ++ni) {
      acc[2 + mi][2 + ni] = mfma16(a23[mi][0], b23[ni][0], acc[2 + mi][2 + ni]);
      acc[2 + mi][2 + ni] = mfma16(a23[mi][1], b23[ni][1], acc[2 + mi][2 + ni]);
    }
  __builtin_amdgcn_s_setprio(0);
  __builtin_amdgcn_s_barrier();            // BB

  // ---- P3: issue (t+2).Aq0,Aq1 (safe after BB); MFMA Q10; end-tile ----
  if constexpr (ISS) {
    stage_q(A, bm, K, t + 2, 0, As, w, lane);
    stage_q(A, bm, K, t + 2, 1, As, w, lane);
  }
  __builtin_amdgcn_s_setprio(1);
#pragma unroll
  for (int mi = 0; mi < 2; ++mi)
#pragma unroll
    for (int ni = 0; ni < 2; ++ni) {
      acc[2 + mi][ni] = mfma16(a23[mi][0], b01[ni][0], acc[2 + mi][ni]);
      acc[2 + mi][ni] = mfma16(a23[mi][1], b01[ni][1], acc[2 + mi][ni]);
    }
  __builtin_amdgcn_s_setprio(0);
  if constexpr (!LAST) {
    vmwait<WEND>();
    __builtin_amdgcn_s_barrier();
  }
}

__global__ __launch_bounds__(512, 2) void k_gemm_proj(
    const u16* __restrict__ A, const u16* __restrict__ Bt,
    const float* __restrict__ scale, float* __restrict__ C,
    int N, long K) {
  __shared__ u16 As[2][128 * 64];
  __shared__ u16 Bs[2][256 * 64];
  const int tid = threadIdx.x, w = tid >> 6, lane = tid & 63;
  const long bm = (long)blockIdx.y * 128;
  const long bn = (long)blockIdx.x * 256;
  const int nt = (int)(K >> 6);

  // prologue: tile0 (6) then tile1 (6); vmcnt(6) -> tile0 landed.
  stage_q(A, bm, K, 0, 0, As, w, lane); stage_q(A, bm, K, 0, 1, As, w, lane);
  stage_q(Bt, bn, K, 0, 0, Bs, w, lane); stage_q(Bt, bn, K, 0, 1, Bs, w, lane);
  stage_q(Bt, bn, K, 0, 2, Bs, w, lane); stage_q(Bt, bn, K, 0, 3, Bs, w, lane);
  stage_q(A, bm, K, 1, 0, As, w, lane); stage_q(A, bm, K, 1, 1, As, w, lane);
  stage_q(Bt, bn, K, 1, 0, Bs, w, lane); stage_q(Bt, bn, K, 1, 1, Bs, w, lane);
  stage_q(Bt, bn, K, 1, 2, Bs, w, lane); stage_q(Bt, bn, K, 1, 3, Bs, w, lane);
  vmwait<6>();
  __builtin_amdgcn_s_barrier();

  f32x4 acc[4][4] = {};
  int t = 0;
  for (; t < nt - 2; ++t)
    pstep<true, false, 6>(t, A, Bt, K, bm, bn, As, Bs, acc, w, lane);
  pstep<false, false, 0>(nt - 2, A, Bt, K, bm, bn, As, Bs, acc, w, lane);
  pstep<false, true, 0>(nt - 1, A, Bt, K, bm, bn, As, Bs, acc, w, lane);

  const int l15 = lane & 15, quad = lane >> 4;
  const int wm = (w & 1) * 64, wn = (w >> 1) * 64;
#pragma unroll
  for (int ni = 0; ni < 4; ++ni) {
    const long col = bn + wn + ni * 16 + l15;
    const float sc = scale[col];
#pragma unroll
    for (int mi = 0; mi < 4; ++mi) {
      const long row0 = bm + wm + mi * 16 + quad * 4;
#pragma unroll
      for (int r = 0; r < 4; ++r)
        C[(row0 + r) * (long)N + col] = acc[mi][ni][r] * sc;
    }
  }
}

// ---------------- fused l2norm(q,k) + V transpose (disjoint regions) --------
__global__ __launch_bounds__(256) void k_norm_vt(u16* __restrict__ qkv,
                                                 const float* __restrict__ qk_gain,
                                                 u16* __restrict__ vt) {
  const int b = blockIdx.x;
  if (b < 4096) {
    const int token = b;
    const int wave = threadIdx.x >> 6, lane = threadIdx.x & 63;
    const float g = qk_gain[0];
    const float qmul = g * g * 1.44269504f * 0.08838834764f;
    u16* rowp = qkv + (long)token * TC3;
#pragma unroll
    for (int s = 0; s < 8; ++s) {
      const int seg = wave * 8 + s;
      const int isK = seg >> 4;
      const int h = seg & 15;
      u16* ptr = rowp + isK * C_ + h * 128 + lane * 2;
      unsigned pv = *(const unsigned*)ptr;
      float a = bf2f((u16)(pv & 0xffffu));
      float bb = bf2f((u16)(pv >> 16));
      float ss = a * a + bb * bb;
#pragma unroll
      for (int m = 1; m <= 32; m <<= 1) ss += __shfl_xor(ss, m);
      float denom = fmaxf(sqrtf(ss), 1e-12f);
      float f = (isK ? 1.0f : qmul) / denom;
      u16 o0 = f2bf(a * f), o1 = f2bf(bb * f);
      *(unsigned*)ptr = (unsigned)o0 | ((unsigned)o1 << 16);
    }
  } else {
    const int v = b - 4096;
    const int t0 = (v & 31) * 64;
    const int h = (v >> 5) & 15;
    const int bz = v >> 9;
    const int t = threadIdx.x & 63;
    const int d0 = threadIdx.x >> 6;       // 0..3
    const long tokbase = (long)bz * T_;
    const u16* src = qkv + (tokbase + t0 + t) * (long)TC3 + 2 * C_ + h * 128;
    u16* dst = vt + ((long)(bz * 16 + h) * 128) * (long)T_ + t0 + t;
#pragma unroll
    for (int dd = 0; dd < 32; ++dd) {
      const int d = dd * 4 + d0;
      dst[(long)d * T_] = src[d];
    }
  }
}

// ---------------- flash attention (causal), m=0 softmax, XCD-pinned ---------
__global__ __launch_bounds__(256, 2) void k_attn(const u16* __restrict__ qkv,
                                                 const u16* __restrict__ vtg,
                                                 u16* __restrict__ y) {
  const int lin = blockIdx.x + 16 * blockIdx.y + 256 * blockIdx.z;
  const int xcd = lin & 7;
  const int idx = lin >> 3;                // 0..63
  const int g   = xcd * 4 + (idx >> 4);    // 0..31: (h,bz) group
  const int qr  = idx & 15;
  const int qt  = (idx & 32) ? (15 - qr) : qr;
  const int h   = g & 15;
  const int bz  = g >> 4;
  const int tid = threadIdx.x, w = tid >> 6, lane = tid & 63;
  const int m31 = lane & 31, hi = lane >> 5;

  __shared__ u16 Ks[2][64 * 128];
  __shared__ u16 Vt[2][128 * 64];

  const long tokbase = (long)bz * T_;
  const int qbase = qt * 128 + w * 32;     // 32 queries per wave
  const u16* vbase = vtg + ((long)(bz * 16 + h) * 128) * (long)T_;
  const u16* kbase = qkv + tokbase * TC3 + C_ + h * 128;

  // Q B-frags (32x32x16: col=lane&31=query, k=d=kc*16+hi*8+i)
  bf16x8 qf[8];
  {
    const u16* qp = qkv + (tokbase + qbase + m31) * (long)TC3 + h * 128 + hi * 8;
#pragma unroll
    for (int kc = 0; kc < 8; ++kc)
      qf[kc] = ld8(qp + kc * 16);
  }

  f32x16 o[4];                             // O^T: d=db*32+crow(reg,hi), q=m31
#pragma unroll
  for (int i = 0; i < 4; ++i)
#pragma unroll
    for (int r = 0; r < 16; ++r) o[i][r] = 0.f;
  f32x4 lacc = {0.f, 0.f, 0.f, 0.f};       // per-lane partial row sums (m==0)

  auto stage = [&](int ktb, int b2) {
#pragma unroll
    for (int j = 0; j < 4; ++j) {
      const int t = w * 4 + j;
      const int p = t * 64 + lane;
      const int r  = p >> 4, ck = p & 15;          // K: row r, chunk ck
      async_cp16(kbase + (long)(ktb + r) * TC3 + ((ck ^ (r & 15)) * 8),
                 &Ks[b2][t * 512]);
      const int d  = p >> 3, cv = p & 7;           // V: row d, chunk cv
      async_cp16(vbase + (long)d * T_ + ktb + ((cv ^ (d & 7)) * 8),
                 &Vt[b2][t * 512]);
    }
  };

  stage(0, 0);
  __syncthreads();                         // drain tile-0 staging
  int b = 0;
  const int ktmax = 2 * qt + 1;

  for (int kt = 0; kt <= ktmax; ++kt) {
    const int ktb = kt * 64;
    if (kt < ktmax) stage(ktb + 64, b ^ 1);

    if (ktb <= qbase + 31) {               // skip fully-masked tiles
      // --- S^T = K.Q^T (32x32x16): C frag key=kb*32+crow, query=m31 ---
      f32x16 sA[2];
      __builtin_amdgcn_s_setprio(1);
#pragma unroll
      for (int kb = 0; kb < 2; ++kb) {
        f32x16 acc;
#pragma unroll
        for (int r = 0; r < 16; ++r) acc[r] = 0.f;
#pragma unroll
        for (int kc = 0; kc < 8; ++kc) {
          bf16x8 kf = ld8(&Ks[b][(kb * 32 + m31) * 128 +
                                 (((2 * kc + hi) ^ (lane & 15)) * 8)]);
          acc = mfma32(kf, qf[kc], acc);
        }
        sA[kb] = acc;
      }
      __builtin_amdgcn_s_setprio(0);

      // --- causal mask (one tile per wave hits this) ---
      if (ktb + 63 > qbase) {
        const int qq = qbase + m31;
#pragma unroll
        for (int kb = 0; kb < 2; ++kb)
#pragma unroll
          for (int r = 0; r < 16; ++r) {
            const int key = ktb + kb * 32 + (r & 3) + 8 * (r >> 2) + 4 * hi;
            if (key > qq) sA[kb][r] = -1e30f;
          }
      }
      // --- m=0 softmax: P = exp2(s), 4-way partial sum chains ---
#pragma unroll
      for (int kb = 0; kb < 2; ++kb)
#pragma unroll
        for (int r = 0; r < 16; ++r) {
          float p = __builtin_amdgcn_exp2f(sA[kb][r]);
          sA[kb][r] = p;
          lacc[r & 3] += p;
        }

      // --- P^T B-frags via cvt_pk + permlane32_swap (pure VALU) ---
      bf16x8 pb[4];
#pragma unroll
      for (int ks = 0; ks < 4; ++ks) {
        const int kb = ks >> 1, j = ks & 1;
        unsigned w0a = cvtpk(sA[kb][8 * j + 0], sA[kb][8 * j + 1]);
        unsigned w1a = cvtpk(sA[kb][8 * j + 2], sA[kb][8 * j + 3]);
        unsigned w0b = cvtpk(sA[kb][8 * j + 4], sA[kb][8 * j + 5]);
        unsigned w1b = cvtpk(sA[kb][8 * j + 6], sA[kb][8 * j + 7]);
        plswap(w0a, w0b);                  // w0a=word0, w0b=word2
        plswap(w1a, w1b);                  // w1a=word1, w1b=word3
        uint4x t; t.x = w0a; t.y = w1a; t.z = w0b; t.w = w1b;
        pb[ks] = __builtin_bit_cast(bf16x8, t);
      }

      // --- O^T += V^T.P^T: A=V^T rows d, k=keys ks*16+hi*8+i ---
      __builtin_amdgcn_s_setprio(1);
#pragma unroll
      for (int db = 0; db < 4; ++db)
#pragma unroll
        for (int ks = 0; ks < 4; ++ks) {
          bf16x8 vf = ld8(&Vt[b][(db * 32 + m31) * 64 +
                                 (((2 * ks + hi) ^ (m31 & 7)) * 8)]);
          o[db] = mfma32(vf, pb[ks], o[db]);
        }
      __builtin_amdgcn_s_setprio(0);
    }

    if (kt < ktmax) __syncthreads();       // drains prefetch + guards buffers
    b ^= 1;
  }

  // --- epilogue: l = sum over both lane halves; write O^T ---
  float lrow = lacc[0] + lacc[1] + lacc[2] + lacc[3];
  lrow += __shfl_xor(lrow, 32);
  const float inv_l = 1.0f / lrow;
  u16* yp = y + (tokbase + qbase + m31) * (long)C_ + h * 128 + 4 * hi;
#pragma unroll
  for (int db = 0; db < 4; ++db)
#pragma unroll
    for (int g2 = 0; g2 < 4; ++g2) {
      u16x4 pk;
#pragma unroll
      for (int r = 0; r < 4; ++r) pk[r] = f2bf(o[db][g2 * 4 + r] * inv_l);
      *(u16x4*)(yp + db * 32 + g2 * 8) = pk;
    }
}

// ---------------------------------------------------------------------------
extern "C" void kernel_launch(void* const* d_in, const int* in_sizes, int n_in,
                              void* d_out, int out_size, void* d_ws, size_t ws_size,
                              hipStream_t stream) {
  const float* x    = (const float*)d_in[0];
  const int*   aw   = (const int*)d_in[1];
  const float* asc  = (const float*)d_in[2];
  const int*   pw   = (const int*)d_in[3];
  const float* psc  = (const float*)d_in[4];
  const float* gain = (const float*)d_in[5];

  char* ws = (char*)d_ws;
  u16* xb  = (u16*)(ws);                         // 16.78 MB (reused as Vt_g)
  u16* wab = (u16*)(ws + 16777216UL);
  u16* wpb = (u16*)(ws + 41943040UL);
  u16* qkv = (u16*)(ws + 50331648UL);
  u16* yb  = (u16*)(ws + 100663296UL);
  u16* vtg = xb;                                 // x_bf16 dead after QKV GEMM

  k_cast_all<<<24576, 256, 0, stream>>>(x, aw, pw, xb, wab, wpb);
  k_gemm256<<<dim3(32, 16), 512, 0, stream>>>(xb, wab, asc, qkv, TC3, (long)C_);
  k_norm_vt<<<5120, 256, 0, stream>>>(qkv, gain, vtg);
  k_attn<<<dim3(16, 16, 2), 256, 0, stream>>>(qkv, vtg, yb);
  k_gemm_proj<<<dim3(8, 32), 512, 0, stream>>>(yb, wpb, psc, (float*)d_out, C_, (long)C_);
}